// Round 7
// baseline (796.290 us; speedup 1.0000x reference)
//
#include <hip/hip_runtime.h>
#include <math.h>

#define NHEADS 12
#define HD 64
#define BB 16
#define NN 1025
#define CC 768
#define MM (BB * NN)                       // 16400
#define QSZ ((size_t)BB * NHEADS * NN * HD)   // 12,595,200
#define NNP 1032                           // padded t-stride for V^T
#define VTSZ ((size_t)BB * NHEADS * HD * NNP)
#define XSZ  ((size_t)MM * CC)             // 12,595,200
#define WTSZ ((size_t)CC * 3 * CC)         // 1,769,472
#define PWSZ ((size_t)CC * CC)             // 589,824

typedef __attribute__((ext_vector_type(8))) short short8;
typedef __attribute__((ext_vector_type(4))) float f32x4;
typedef __attribute__((ext_vector_type(4))) unsigned short us4;
typedef unsigned short us;

__device__ __forceinline__ int imin(int a, int b) { return a < b ? a : b; }

__device__ __forceinline__ us f2bf(float f) {   // RTNE fp32->bf16 bits
    unsigned u = __float_as_uint(f);
    u += 0x7FFF + ((u >> 16) & 1);
    return (us)(u >> 16);
}
__device__ __forceinline__ float bf2f(us b) {
    return __uint_as_float(((unsigned)b) << 16);
}

// ---------------- split_x: fp32 -> bf16 hi/lo planes -------------------------------
__global__ __launch_bounds__(256) void split_x(const float* __restrict__ src,
                                               us* __restrict__ hi, us* __restrict__ lo) {
    size_t i = ((size_t)blockIdx.x * 256 + threadIdx.x) * 8;
    float4 a = *(const float4*)(src + i);
    float4 b = *(const float4*)(src + i + 4);
    float v[8] = {a.x, a.y, a.z, a.w, b.x, b.y, b.z, b.w};
    short8 h, l;
#pragma unroll
    for (int j = 0; j < 8; ++j) {
        us hb = f2bf(v[j]);
        h[j] = (short)hb;
        l[j] = (short)f2bf(v[j] - bf2f(hb));
    }
    *(short8*)(hi + i) = h;
    *(short8*)(lo + i) = l;
}

// ---------------- tsplit: W [K][N] fp32 -> W^T hi/lo [N][K] bf16 -------------------
__global__ __launch_bounds__(256) void tsplit(const float* __restrict__ w,
                                              us* __restrict__ thi, us* __restrict__ tlo,
                                              int K, int N) {
    __shared__ float tile[64][65];
    const int t = threadIdx.x;
    const int n0 = blockIdx.x * 64, k0 = blockIdx.y * 64;
    {
        int kr = t & 63, so = t >> 6;
#pragma unroll
        for (int g = 0; g < 4; ++g) {
            int c = (so * 4 + g) * 4;
            float4 v = *(const float4*)(w + (size_t)(k0 + kr) * N + n0 + c);
            tile[kr][c + 0] = v.x; tile[kr][c + 1] = v.y;
            tile[kr][c + 2] = v.z; tile[kr][c + 3] = v.w;
        }
    }
    __syncthreads();
    int nr = t & 63, half = t >> 6;
    short8 h0, l0, h1, l1;
#pragma unroll
    for (int j = 0; j < 8; ++j) {
        float v = tile[half * 16 + j][nr];
        us hb = f2bf(v);
        h0[j] = (short)hb; l0[j] = (short)f2bf(v - bf2f(hb));
    }
#pragma unroll
    for (int j = 0; j < 8; ++j) {
        float v = tile[half * 16 + 8 + j][nr];
        us hb = f2bf(v);
        h1[j] = (short)hb; l1[j] = (short)f2bf(v - bf2f(hb));
    }
    size_t o = (size_t)(n0 + nr) * K + k0 + half * 16;
    *(short8*)(thi + o) = h0; *(short8*)(thi + o + 8) = h1;
    *(short8*)(tlo + o) = l0; *(short8*)(tlo + o + 8) = l1;
}

// ---------------- gemm_mfma: reg-prefetch dbuf, XOR-swizzled 128B LDS rows ---------
// Row r of each operand tile: [hi 64B | lo 64B], 16B slots XOR'd with (r&7).
template<int MODE>
__global__ __launch_bounds__(256, 3) void gemm_mfma(
    const us* __restrict__ Ahi, const us* __restrict__ Alo,
    const us* __restrict__ Bhi, const us* __restrict__ Blo,
    us* __restrict__ Qhi, us* __restrict__ Qlo,
    us* __restrict__ Khi, us* __restrict__ Klo,
    us* __restrict__ Vth,
    float* __restrict__ fout, const float* __restrict__ bias) {
    __shared__ __align__(16) char lds[32768];
    char* ldsA = lds;
    char* ldsB = lds + 16384;
    const int tid = threadIdx.x;
    const int lane = tid & 63, wv = tid >> 6;
    const int wn = wv >> 1, wm = wv & 1;
    const int n0 = blockIdx.x * 128, m0 = blockIdx.y * 128;

    f32x4 acc[4][4];
    const f32x4 fz = {0.f, 0.f, 0.f, 0.f};
#pragma unroll
    for (int a = 0; a < 4; ++a)
#pragma unroll
        for (int b = 0; b < 4; ++b) acc[a][b] = fz;

    const int srow = tid & 127, pl = tid >> 7;   // thread stages plane pl of row srow
    const us* baseA = (pl ? Alo : Ahi) + (size_t)(n0 + srow) * CC;
    const us* baseB = (pl ? Blo : Bhi) + (size_t)imin(m0 + srow, MM - 1) * CC;
    const int swz = (srow & 7) << 4;
    char* dstA = ldsA + srow * 128;
    char* dstB = ldsB + srow * 128;

    short8 pa[4], pb[4];
    auto prefetch = [&](int k0) {
#pragma unroll
        for (int c = 0; c < 4; ++c) {
            pa[c] = *(const short8*)(baseA + k0 + c * 8);
            pb[c] = *(const short8*)(baseB + k0 + c * 8);
        }
    };
    prefetch(0);

    for (int t = 0; t < CC / 32; ++t) {
        // ---- write prefetched K-slab to LDS (swizzled) ----
#pragma unroll
        for (int c = 0; c < 4; ++c) {
            int off = ((pl << 6) + (c << 4)) ^ swz;
            *(short8*)(dstA + off) = pa[c];
            *(short8*)(dstB + off) = pb[c];
        }
        __syncthreads();
        if (t < CC / 32 - 1) prefetch((t + 1) * 32);   // in flight across compute

        short8 af[4][2];
        const int ko = (lane >> 4) << 4;               // k-slot byte offset
#pragma unroll
        for (int nc = 0; nc < 4; ++nc) {
            int ra = wn * 64 + nc * 16 + (lane & 15);
            const char* pA = ldsA + ra * 128;
            int rs = (ra & 7) << 4;
            af[nc][0] = *(const short8*)(pA + (ko ^ rs));          // hi
            af[nc][1] = *(const short8*)(pA + ((64 + ko) ^ rs));   // lo
        }
        __builtin_amdgcn_s_setprio(1);
#pragma unroll
        for (int mc = 0; mc < 4; ++mc) {
            int rb = wm * 64 + mc * 16 + (lane & 15);
            const char* pB = ldsB + rb * 128;
            int rs = (rb & 7) << 4;
            short8 b0 = *(const short8*)(pB + (ko ^ rs));
            short8 b1 = *(const short8*)(pB + ((64 + ko) ^ rs));
#pragma unroll
            for (int nc = 0; nc < 4; ++nc) {
                acc[nc][mc] = __builtin_amdgcn_mfma_f32_16x16x32_bf16(af[nc][0], b0, acc[nc][mc], 0, 0, 0);
                acc[nc][mc] = __builtin_amdgcn_mfma_f32_16x16x32_bf16(af[nc][0], b1, acc[nc][mc], 0, 0, 0);
                acc[nc][mc] = __builtin_amdgcn_mfma_f32_16x16x32_bf16(af[nc][1], b0, acc[nc][mc], 0, 0, 0);
            }
        }
        __builtin_amdgcn_s_setprio(0);
        __syncthreads();
    }

#pragma unroll
    for (int mc = 0; mc < 4; ++mc) {
        int m = m0 + wm * 64 + mc * 16 + (lane & 15);
        if (m >= MM) continue;
        if (MODE == 0) {
            int b = m / NN, t = m - b * NN;
#pragma unroll
            for (int nc = 0; nc < 4; ++nc) {
                int n = n0 + wn * 64 + nc * 16 + ((lane >> 4) << 2);
                int s = n0 / CC;
                int nin = n - s * CC;
                int head = nin >> 6, d0 = nin & 63;
                int bh = b * NHEADS + head;
                if (s < 2) {
                    us4 h4, l4;
#pragma unroll
                    for (int r = 0; r < 4; ++r) {
                        float v = acc[nc][mc][r];
                        us hb = f2bf(v);
                        h4[r] = hb; l4[r] = f2bf(v - bf2f(hb));
                    }
                    size_t idx = ((size_t)bh * NN + t) * HD + d0;
                    if (s == 0) { *(us4*)(Qhi + idx) = h4; *(us4*)(Qlo + idx) = l4; }
                    else        { *(us4*)(Khi + idx) = h4; *(us4*)(Klo + idx) = l4; }
                } else {
#pragma unroll
                    for (int r = 0; r < 4; ++r) {
                        float v = acc[nc][mc][r];
                        size_t idx = ((size_t)bh * HD + d0 + r) * NNP + t;
                        Vth[idx] = f2bf(v);
                        if (t == NN - 1) {
#pragma unroll
                            for (int tt = 1; tt <= 7; ++tt) Vth[idx + tt] = 0;
                        }
                    }
                }
            }
        } else {
#pragma unroll
            for (int nc = 0; nc < 4; ++nc) {
                int n = n0 + wn * 64 + nc * 16 + ((lane >> 4) << 2);
                float4 o = {acc[nc][mc][0] + bias[n + 0], acc[nc][mc][1] + bias[n + 1],
                            acc[nc][mc][2] + bias[n + 2], acc[nc][mc][3] + bias[n + 3]};
                *(float4*)(fout + (size_t)m * CC + n) = o;
            }
        }
    }
}

// ---------------- norm_rope (unchanged) --------------------------------------------
__global__ __launch_bounds__(256) void norm_rope(us* __restrict__ Qhi, us* __restrict__ Qlo,
                                                 us* __restrict__ Khi, us* __restrict__ Klo,
                                                 const float* __restrict__ qw,
                                                 const float* __restrict__ kw) {
    const int lane = threadIdx.x & 63;
    const int widx = threadIdx.x >> 6;
    const int rid  = blockIdx.x * 4 + widx;
    const bool isq = (blockIdx.y == 0);
    us* Ph = (isq ? Qhi : Khi);
    us* Pl = (isq ? Qlo : Klo);
    const float* w = isq ? qw : kw;
    const int t = rid % NN;
    size_t base = (size_t)rid * HD + lane;

    float v = bf2f(Ph[base]) + bf2f(Pl[base]);
    float ss = v * v;
#pragma unroll
    for (int o = 32; o; o >>= 1) ss += __shfl_xor(ss, o);
    float r = 1.0f / sqrtf(ss * (1.0f / 64.0f) + 1e-6f);
    v = v * r * w[lane];

    float partner = __shfl_xor(v, 32);
    if (t > 0) {
        int p   = t - 1;
        int pos = (lane < 32) ? (p & 31) : (p >> 5);
        int j   = lane & 15;
        float invf = exp2f((float)j * (-13.287712379549449f / 16.0f));
        float ang  = (float)pos * invf;
        float c = cosf(ang), sn = sinf(ang);
        float rh = (lane < 32) ? -partner : partner;
        v = v * c + rh * sn;
    }
    if (isq) v *= 0.125f;
    us hb = f2bf(v);
    Ph[base] = hb;
    Pl[base] = f2bf(v - bf2f(hb));
}

// ---------------- attn: MFMA flash attention, reg-prefetch double-buffer -----------
__global__ __launch_bounds__(256, 4) void attn_mfma(
    const us* __restrict__ Qhi, const us* __restrict__ Qlo,
    const us* __restrict__ Khi, const us* __restrict__ Klo,
    const us* __restrict__ Vth,
    us* __restrict__ Ohi, us* __restrict__ Olo) {
    __shared__ __align__(16) char smem[32768];
    const int tid = threadIdx.x;
    const int lane = tid & 63, wv = tid >> 6;

    int lin = blockIdx.x;
    int xcd = lin & 7, loc = lin >> 3;
    int bh  = (loc / 17) * 8 + xcd;
    int qb  = loc - (loc / 17) * 17;
    const int q0 = qb * 64;

    const size_t kbase0 = (size_t)bh * NN * HD;
    const size_t vbase0 = (size_t)bh * HD * NNP;

    short8 qfh[2], qfl[2];
    {
        int qr = imin(q0 + (wv << 4) + (lane & 15), NN - 1);
        const us* qp  = Qhi + kbase0 + (size_t)qr * HD + ((lane >> 4) << 3);
        const us* qp2 = Qlo + kbase0 + (size_t)qr * HD + ((lane >> 4) << 3);
        qfh[0] = *(const short8*)(qp);
        qfh[1] = *(const short8*)(qp + 32);
        qfl[0] = *(const short8*)(qp2);
        qfl[1] = *(const short8*)(qp2 + 32);
    }

    f32x4 oa[4];
    const f32x4 fz = {0.f, 0.f, 0.f, 0.f};
#pragma unroll
    for (int db = 0; db < 4; ++db) oa[db] = fz;
    float m[4]    = {-INFINITY, -INFINITY, -INFINITY, -INFINITY};
    float lsum[4] = {0.f, 0.f, 0.f, 0.f};

    const int PB = 24576 + wv * 2048;

    short8 pkh[2], pkl[2], pvh[2];
    const int srow = (wv << 4) + (lane >> 3);
    const int g    = lane & 7;
    auto issue_loads = [&](int j0) {
#pragma unroll
        for (int i = 0; i < 2; ++i) {
            int row = srow + (i << 3);
            int krow = imin(j0 + row, NN - 1);
            pkh[i] = *(const short8*)(Khi + kbase0 + (size_t)krow * HD + (g << 3));
            pkl[i] = *(const short8*)(Klo + kbase0 + (size_t)krow * HD + (g << 3));
            int k0 = j0 + (g << 3);
            if (k0 > 1024) k0 = 1024;
            pvh[i] = *(const short8*)(Vth + vbase0 + (size_t)row * NNP + k0);
        }
    };
    issue_loads(0);

    for (int t = 0; t < 17; ++t) {
        const int j0 = t * 64;
#pragma unroll
        for (int i = 0; i < 2; ++i) {
            int row = srow + (i << 3);
            int off = row * 128 + ((g << 4) ^ ((row & 7) << 4));
            *(short8*)(smem + off)         = pkh[i];
            *(short8*)(smem + 8192 + off)  = pkl[i];
            *(short8*)(smem + 16384 + off) = pvh[i];
        }
        __syncthreads();
        if (t < 16) issue_loads(j0 + 64);

        f32x4 sc[4];
#pragma unroll
        for (int c = 0; c < 4; ++c) sc[c] = fz;
        __builtin_amdgcn_s_setprio(1);
#pragma unroll
        for (int ks = 0; ks < 2; ++ks) {
#pragma unroll
            for (int c = 0; c < 4; ++c) {
                int row  = (c << 4) + (lane & 15);
                int boff = row * 128 + (((ks << 6) + ((lane >> 4) << 4)) ^ ((row & 7) << 4));
                short8 kfh = *(const short8*)(smem + boff);
                short8 kfl = *(const short8*)(smem + 8192 + boff);
                sc[c] = __builtin_amdgcn_mfma_f32_16x16x32_bf16(qfh[ks], kfh, sc[c], 0, 0, 0);
                sc[c] = __builtin_amdgcn_mfma_f32_16x16x32_bf16(qfh[ks], kfl, sc[c], 0, 0, 0);
                sc[c] = __builtin_amdgcn_mfma_f32_16x16x32_bf16(qfl[ks], kfh, sc[c], 0, 0, 0);
            }
        }
        __builtin_amdgcn_s_setprio(0);

        int kq = j0 + (lane & 15);
        const f32x4 fneg = {-1e30f, -1e30f, -1e30f, -1e30f};
#pragma unroll
        for (int c = 0; c < 4; ++c)
            if (kq + (c << 4) >= NN) sc[c] = fneg;

#pragma unroll
        for (int r = 0; r < 4; ++r) {
            float rm = fmaxf(fmaxf(sc[0][r], sc[1][r]), fmaxf(sc[2][r], sc[3][r]));
            rm = fmaxf(rm, __shfl_xor(rm, 1));
            rm = fmaxf(rm, __shfl_xor(rm, 2));
            rm = fmaxf(rm, __shfl_xor(rm, 4));
            rm = fmaxf(rm, __shfl_xor(rm, 8));
            float mnew = fmaxf(m[r], rm);
            float corr = __expf(m[r] - mnew);
            m[r] = mnew;
            int prow  = ((lane >> 4) << 2) + r;
            int rowsw = (prow & 7) << 4;
            float rs = 0.f;
#pragma unroll
            for (int c = 0; c < 4; ++c) {
                float p = __expf(sc[c][r] - mnew);
                rs += p;
                int colb = ((c << 4) + (lane & 15)) << 1;
                *(us*)(smem + PB + prow * 128 + (colb ^ rowsw)) = f2bf(p);
            }
            rs += __shfl_xor(rs, 1);
            rs += __shfl_xor(rs, 2);
            rs += __shfl_xor(rs, 4);
            rs += __shfl_xor(rs, 8);
            lsum[r] = lsum[r] * corr + rs;
#pragma unroll
            for (int db = 0; db < 4; ++db) oa[db][r] *= corr;
        }

        __builtin_amdgcn_s_setprio(1);
#pragma unroll
        for (int ks = 0; ks < 2; ++ks) {
            int prow = lane & 15;
            int poff = PB + prow * 128 + (((ks << 6) + ((lane >> 4) << 4)) ^ ((prow & 7) << 4));
            short8 pah = *(const short8*)(smem + poff);
#pragma unroll
            for (int db = 0; db < 4; ++db) {
                int vrow = (db << 4) + (lane & 15);
                int voff = vrow * 128 + (((ks << 6) + ((lane >> 4) << 4)) ^ ((vrow & 7) << 4));
                short8 vfh = *(const short8*)(smem + 16384 + voff);
                oa[db] = __builtin_amdgcn_mfma_f32_16x16x32_bf16(pah, vfh, oa[db], 0, 0, 0);
            }
        }
        __builtin_amdgcn_s_setprio(0);
        __syncthreads();
    }

    const int b = bh / NHEADS, h = bh - b * NHEADS;
#pragma unroll
    for (int r = 0; r < 4; ++r) {
        int q = q0 + (wv << 4) + ((lane >> 4) << 2) + r;
        if (q < NN) {
            float inv = 1.0f / lsum[r];
#pragma unroll
            for (int db = 0; db < 4; ++db) {
                int d = (db << 4) + (lane & 15);
                float v = oa[db][r] * inv;
                size_t idx = ((size_t)b * NN + q) * CC + h * HD + d;
                us hb = f2bf(v);
                Ohi[idx] = hb;
                Olo[idx] = f2bf(v - bf2f(hb));
            }
        }
    }
}

extern "C" void kernel_launch(void* const* d_in, const int* in_sizes, int n_in,
                              void* d_out, int out_size, void* d_ws, size_t ws_size,
                              hipStream_t stream) {
    const float* x      = (const float*)d_in[0];
    const float* qkv_w  = (const float*)d_in[1];
    const float* proj_w = (const float*)d_in[2];
    const float* proj_b = (const float*)d_in[3];
    const float* qnw    = (const float*)d_in[4];
    const float* knw    = (const float*)d_in[5];

    us* p = (us*)d_ws;
    us* Qhi = p;                 p += QSZ;
    us* Qlo = p;                 p += QSZ;
    us* Khi = p;                 p += QSZ;
    us* Klo = p;                 p += QSZ;
    us* Vth = p;                 p += VTSZ;
    us* Xhi = p;                 p += XSZ;   // reused as Ohi after qkv GEMM
    us* Xlo = p;                 p += XSZ;   // reused as Olo
    us* Wthi = p;                p += WTSZ;
    us* Wtlo = p;                p += WTSZ;
    us* Pwhi = p;                p += PWSZ;
    us* Pwlo = p;                p += PWSZ;

    split_x<<<dim3((int)(XSZ / 8 / 256)), 256, 0, stream>>>(x, Xhi, Xlo);
    tsplit<<<dim3(3 * CC / 64, CC / 64), 256, 0, stream>>>(qkv_w, Wthi, Wtlo, CC, 3 * CC);
    tsplit<<<dim3(CC / 64, CC / 64), 256, 0, stream>>>(proj_w, Pwhi, Pwlo, CC, CC);

    gemm_mfma<0><<<dim3(3 * CC / 128, (MM + 127) / 128), 256, 0, stream>>>(
        Wthi, Wtlo, Xhi, Xlo, Qhi, Qlo, Khi, Klo, Vth, nullptr, nullptr);
    norm_rope<<<dim3(BB * NHEADS * NN / 4, 2), 256, 0, stream>>>(Qhi, Qlo, Khi, Klo, qnw, knw);
    attn_mfma<<<dim3(8 * 408), 256, 0, stream>>>(Qhi, Qlo, Khi, Klo, Vth, Xhi, Xlo);
    gemm_mfma<1><<<dim3(CC / 128, (MM + 127) / 128), 256, 0, stream>>>(
        Pwhi, Pwlo, Xhi, Xlo, nullptr, nullptr, nullptr, nullptr, nullptr,
        (float*)d_out, proj_b);
}

// Round 9
// 554.964 us; speedup vs baseline: 1.4348x; 1.4348x over previous
//
#include <hip/hip_runtime.h>
#include <math.h>

#define NHEADS 12
#define HD 64
#define BB 16
#define NN 1025
#define CC 768
#define MM (BB * NN)                       // 16400
#define QSZ ((size_t)BB * NHEADS * NN * HD)   // 12,595,200
#define NNP 1032                           // padded t-stride for V^T
#define VTSZ ((size_t)BB * NHEADS * HD * NNP)
#define CBS 1536                           // combined-layout row stride (elems): [kblk][hi32|lo32]

typedef __attribute__((ext_vector_type(8))) short short8;
typedef __attribute__((ext_vector_type(4))) float f32x4;
typedef __attribute__((ext_vector_type(4))) unsigned short us4;
typedef unsigned short us;

typedef __attribute__((address_space(3))) unsigned int lds_u32;
typedef const __attribute__((address_space(1))) unsigned int g_u32;

__device__ __forceinline__ void gload16(const void* g, void* l) {
    __builtin_amdgcn_global_load_lds((g_u32*)g, (lds_u32*)l, 16, 0, 0);
}

__device__ __forceinline__ int imin(int a, int b) { return a < b ? a : b; }

__device__ __forceinline__ us f2bf(float f) {   // RTNE fp32->bf16 bits
    unsigned u = __float_as_uint(f);
    u += 0x7FFF + ((u >> 16) & 1);
    return (us)(u >> 16);
}
__device__ __forceinline__ float bf2f(us b) {
    return __uint_as_float(((unsigned)b) << 16);
}

// ---------------- split_x: fp32 -> combined hi/lo layout [row][kblk][hi32|lo32] ----
__global__ __launch_bounds__(256) void split_x(const float* __restrict__ src,
                                               us* __restrict__ xc) {
    size_t gid = (size_t)blockIdx.x * 256 + threadIdx.x;
    size_t e = gid * 8;
    int row = (int)(e / CC), k = (int)(e % CC);
    float4 a = *(const float4*)(src + e);
    float4 b = *(const float4*)(src + e + 4);
    float v[8] = {a.x, a.y, a.z, a.w, b.x, b.y, b.z, b.w};
    short8 h, l;
#pragma unroll
    for (int j = 0; j < 8; ++j) {
        us hb = f2bf(v[j]);
        h[j] = (short)hb;
        l[j] = (short)f2bf(v[j] - bf2f(hb));
    }
    size_t o = (size_t)row * CBS + (k >> 5) * 64 + (k & 31);
    *(short8*)(xc + o)      = h;
    *(short8*)(xc + o + 32) = l;
}

// ---------------- tsplit: W [K][N] fp32 -> W^T combined [N][kblk][hi32|lo32] -------
__global__ __launch_bounds__(256) void tsplit(const float* __restrict__ w,
                                              us* __restrict__ wc, int N) {
    __shared__ float tile[64][65];
    const int t = threadIdx.x;
    const int n0 = blockIdx.x * 64, k0 = blockIdx.y * 64;
    {
        int kr = t & 63, so = t >> 6;
#pragma unroll
        for (int g = 0; g < 4; ++g) {
            int c = (so * 4 + g) * 4;
            float4 v = *(const float4*)(w + (size_t)(k0 + kr) * N + n0 + c);
            tile[kr][c + 0] = v.x; tile[kr][c + 1] = v.y;
            tile[kr][c + 2] = v.z; tile[kr][c + 3] = v.w;
        }
    }
    __syncthreads();
    int nr = t & 63, half = t >> 6;     // 16 consecutive k per thread
#pragma unroll
    for (int blk = 0; blk < 2; ++blk) {
        short8 h, l;
#pragma unroll
        for (int j = 0; j < 8; ++j) {
            float v = tile[half * 16 + blk * 8 + j][nr];
            us hb = f2bf(v);
            h[j] = (short)hb; l[j] = (short)f2bf(v - bf2f(hb));
        }
        int kg = k0 + half * 16 + blk * 8;
        size_t o = (size_t)(n0 + nr) * CBS + (kg >> 5) * 64 + (kg & 31);
        *(short8*)(wc + o)      = h;
        *(short8*)(wc + o + 32) = l;
    }
}

// ---------------- gemm_mfma: global_load_lds staging, pre-swizzled source ----------
// LDS rows 128B; slot s of row r holds chunk s^(r&7); read XORs back.
template<int MODE>
__global__ __launch_bounds__(256) void gemm_mfma(
    const us* __restrict__ A,      // W^T combined [N][CBS]
    const us* __restrict__ B,      // X/O combined [M][CBS]
    us* __restrict__ Qhi, us* __restrict__ Qlo,
    us* __restrict__ Khi, us* __restrict__ Klo,
    us* __restrict__ Vth,
    float* __restrict__ fout, const float* __restrict__ bias) {
    __shared__ __align__(16) char lds[32768];
    char* ldsA = lds;
    char* ldsB = lds + 16384;
    const int tid = threadIdx.x;
    const int lane = tid & 63, wv = tid >> 6;
    const int wn = wv >> 1, wm = wv & 1;
    const int n0 = blockIdx.x * 128, m0 = blockIdx.y * 128;

    f32x4 acc[4][4];
    const f32x4 fz = {0.f, 0.f, 0.f, 0.f};
#pragma unroll
    for (int a = 0; a < 4; ++a)
#pragma unroll
        for (int b = 0; b < 4; ++b) acc[a][b] = fz;

    // per-lane pre-swizzled global source offsets (chunk c = (lane&7) ^ (lane>>3))
    const int lrow = lane >> 3;
    const int c    = (lane & 7) ^ lrow;
    size_t aoff[4], boff[4];
#pragma unroll
    for (int i = 0; i < 4; ++i) {
        int ra = n0 + wv * 32 + i * 8 + lrow;
        int rb = imin(m0 + wv * 32 + i * 8 + lrow, MM - 1);
        aoff[i] = (size_t)ra * CBS + c * 8;
        boff[i] = (size_t)rb * CBS + c * 8;
    }

    for (int t = 0; t < CC / 32; ++t) {
        const size_t kb = (size_t)t * 64;
#pragma unroll
        for (int i = 0; i < 4; ++i) {
            gload16(A + aoff[i] + kb, ldsA + (wv * 32 + i * 8) * 128);
            gload16(B + boff[i] + kb, ldsB + (wv * 32 + i * 8) * 128);
        }
        __syncthreads();   // drains vmcnt -> LDS tile valid

        short8 af[4][2];
        const int ko = (lane >> 4) << 4;
#pragma unroll
        for (int nc = 0; nc < 4; ++nc) {
            int ra = wn * 64 + nc * 16 + (lane & 15);
            const char* pA = ldsA + ra * 128;
            int rs = (ra & 7) << 4;
            af[nc][0] = *(const short8*)(pA + (ko ^ rs));          // hi
            af[nc][1] = *(const short8*)(pA + ((64 + ko) ^ rs));   // lo
        }
        __builtin_amdgcn_s_setprio(1);
#pragma unroll
        for (int mc = 0; mc < 4; ++mc) {
            int rb = wm * 64 + mc * 16 + (lane & 15);
            const char* pB = ldsB + rb * 128;
            int rs = (rb & 7) << 4;
            short8 b0 = *(const short8*)(pB + (ko ^ rs));
            short8 b1 = *(const short8*)(pB + ((64 + ko) ^ rs));
#pragma unroll
            for (int nc = 0; nc < 4; ++nc) {
                acc[nc][mc] = __builtin_amdgcn_mfma_f32_16x16x32_bf16(af[nc][0], b0, acc[nc][mc], 0, 0, 0);
                acc[nc][mc] = __builtin_amdgcn_mfma_f32_16x16x32_bf16(af[nc][0], b1, acc[nc][mc], 0, 0, 0);
                acc[nc][mc] = __builtin_amdgcn_mfma_f32_16x16x32_bf16(af[nc][1], b0, acc[nc][mc], 0, 0, 0);
            }
        }
        __builtin_amdgcn_s_setprio(0);
        __syncthreads();
    }

#pragma unroll
    for (int mc = 0; mc < 4; ++mc) {
        int m = m0 + wm * 64 + mc * 16 + (lane & 15);
        if (m >= MM) continue;
        if (MODE == 0) {
            int b = m / NN, t = m - b * NN;
#pragma unroll
            for (int nc = 0; nc < 4; ++nc) {
                int n = n0 + wn * 64 + nc * 16 + ((lane >> 4) << 2);
                int s = n0 / CC;
                int nin = n - s * CC;
                int head = nin >> 6, d0 = nin & 63;
                int bh = b * NHEADS + head;
                if (s < 2) {
                    us4 h4, l4;
#pragma unroll
                    for (int r = 0; r < 4; ++r) {
                        float v = acc[nc][mc][r];
                        us hb = f2bf(v);
                        h4[r] = hb; l4[r] = f2bf(v - bf2f(hb));
                    }
                    size_t idx = ((size_t)bh * NN + t) * HD + d0;
                    if (s == 0) { *(us4*)(Qhi + idx) = h4; *(us4*)(Qlo + idx) = l4; }
                    else        { *(us4*)(Khi + idx) = h4; *(us4*)(Klo + idx) = l4; }
                } else {
#pragma unroll
                    for (int r = 0; r < 4; ++r) {
                        float v = acc[nc][mc][r];
                        size_t idx = ((size_t)bh * HD + d0 + r) * NNP + t;
                        Vth[idx] = f2bf(v);
                        if (t == NN - 1) {
#pragma unroll
                            for (int tt = 1; tt <= 7; ++tt) Vth[idx + tt] = 0;
                        }
                    }
                }
            }
        } else {
#pragma unroll
            for (int nc = 0; nc < 4; ++nc) {
                int n = n0 + wn * 64 + nc * 16 + ((lane >> 4) << 2);
                float4 o = {acc[nc][mc][0] + bias[n + 0], acc[nc][mc][1] + bias[n + 1],
                            acc[nc][mc][2] + bias[n + 2], acc[nc][mc][3] + bias[n + 3]};
                *(float4*)(fout + (size_t)m * CC + n) = o;
            }
        }
    }
}

// ---------------- norm_rope (unchanged) --------------------------------------------
__global__ __launch_bounds__(256) void norm_rope(us* __restrict__ Qhi, us* __restrict__ Qlo,
                                                 us* __restrict__ Khi, us* __restrict__ Klo,
                                                 const float* __restrict__ qw,
                                                 const float* __restrict__ kw) {
    const int lane = threadIdx.x & 63;
    const int widx = threadIdx.x >> 6;
    const int rid  = blockIdx.x * 4 + widx;
    const bool isq = (blockIdx.y == 0);
    us* Ph = (isq ? Qhi : Khi);
    us* Pl = (isq ? Qlo : Klo);
    const float* w = isq ? qw : kw;
    const int t = rid % NN;
    size_t base = (size_t)rid * HD + lane;

    float v = bf2f(Ph[base]) + bf2f(Pl[base]);
    float ss = v * v;
#pragma unroll
    for (int o = 32; o; o >>= 1) ss += __shfl_xor(ss, o);
    float r = 1.0f / sqrtf(ss * (1.0f / 64.0f) + 1e-6f);
    v = v * r * w[lane];

    float partner = __shfl_xor(v, 32);
    if (t > 0) {
        int p   = t - 1;
        int pos = (lane < 32) ? (p & 31) : (p >> 5);
        int j   = lane & 15;
        float invf = exp2f((float)j * (-13.287712379549449f / 16.0f));
        float ang  = (float)pos * invf;
        float c = cosf(ang), sn = sinf(ang);
        float rh = (lane < 32) ? -partner : partner;
        v = v * c + rh * sn;
    }
    if (isq) v *= 0.125f;
    us hb = f2bf(v);
    Ph[base] = hb;
    Pl[base] = f2bf(v - bf2f(hb));
}

// ---------------- attn: MFMA flash attention (epilogue -> combined O layout) -------
__global__ __launch_bounds__(256, 4) void attn_mfma(
    const us* __restrict__ Qhi, const us* __restrict__ Qlo,
    const us* __restrict__ Khi, const us* __restrict__ Klo,
    const us* __restrict__ Vth,
    us* __restrict__ OC) {
    __shared__ __align__(16) char smem[32768];
    const int tid = threadIdx.x;
    const int lane = tid & 63, wv = tid >> 6;

    int lin = blockIdx.x;
    int xcd = lin & 7, loc = lin >> 3;
    int bh  = (loc / 17) * 8 + xcd;
    int qb  = loc - (loc / 17) * 17;
    const int q0 = qb * 64;

    const size_t kbase0 = (size_t)bh * NN * HD;
    const size_t vbase0 = (size_t)bh * HD * NNP;

    short8 qfh[2], qfl[2];
    {
        int qr = imin(q0 + (wv << 4) + (lane & 15), NN - 1);
        const us* qp  = Qhi + kbase0 + (size_t)qr * HD + ((lane >> 4) << 3);
        const us* qp2 = Qlo + kbase0 + (size_t)qr * HD + ((lane >> 4) << 3);
        qfh[0] = *(const short8*)(qp);
        qfh[1] = *(const short8*)(qp + 32);
        qfl[0] = *(const short8*)(qp2);
        qfl[1] = *(const short8*)(qp2 + 32);
    }

    f32x4 oa[4];
    const f32x4 fz = {0.f, 0.f, 0.f, 0.f};
#pragma unroll
    for (int db = 0; db < 4; ++db) oa[db] = fz;
    float m[4]    = {-INFINITY, -INFINITY, -INFINITY, -INFINITY};
    float lsum[4] = {0.f, 0.f, 0.f, 0.f};

    const int PB = 24576 + wv * 2048;

    short8 pkh[2], pkl[2], pvh[2];
    const int srow = (wv << 4) + (lane >> 3);
    const int g    = lane & 7;
    auto issue_loads = [&](int j0) {
#pragma unroll
        for (int i = 0; i < 2; ++i) {
            int row = srow + (i << 3);
            int krow = imin(j0 + row, NN - 1);
            pkh[i] = *(const short8*)(Khi + kbase0 + (size_t)krow * HD + (g << 3));
            pkl[i] = *(const short8*)(Klo + kbase0 + (size_t)krow * HD + (g << 3));
            int k0 = j0 + (g << 3);
            if (k0 > 1024) k0 = 1024;
            pvh[i] = *(const short8*)(Vth + vbase0 + (size_t)row * NNP + k0);
        }
    };
    issue_loads(0);

    for (int t = 0; t < 17; ++t) {
        const int j0 = t * 64;
#pragma unroll
        for (int i = 0; i < 2; ++i) {
            int row = srow + (i << 3);
            int off = row * 128 + ((g << 4) ^ ((row & 7) << 4));
            *(short8*)(smem + off)         = pkh[i];
            *(short8*)(smem + 8192 + off)  = pkl[i];
            *(short8*)(smem + 16384 + off) = pvh[i];
        }
        __syncthreads();
        if (t < 16) issue_loads(j0 + 64);

        f32x4 sc[4];
#pragma unroll
        for (int c = 0; c < 4; ++c) sc[c] = fz;
        __builtin_amdgcn_s_setprio(1);
#pragma unroll
        for (int ks = 0; ks < 2; ++ks) {
#pragma unroll
            for (int c = 0; c < 4; ++c) {
                int row  = (c << 4) + (lane & 15);
                int boff = row * 128 + (((ks << 6) + ((lane >> 4) << 4)) ^ ((row & 7) << 4));
                short8 kfh = *(const short8*)(smem + boff);
                short8 kfl = *(const short8*)(smem + 8192 + boff);
                sc[c] = __builtin_amdgcn_mfma_f32_16x16x32_bf16(qfh[ks], kfh, sc[c], 0, 0, 0);
                sc[c] = __builtin_amdgcn_mfma_f32_16x16x32_bf16(qfh[ks], kfl, sc[c], 0, 0, 0);
                sc[c] = __builtin_amdgcn_mfma_f32_16x16x32_bf16(qfl[ks], kfh, sc[c], 0, 0, 0);
            }
        }
        __builtin_amdgcn_s_setprio(0);

        int kq = j0 + (lane & 15);
        const f32x4 fneg = {-1e30f, -1e30f, -1e30f, -1e30f};
#pragma unroll
        for (int c = 0; c < 4; ++c)
            if (kq + (c << 4) >= NN) sc[c] = fneg;

#pragma unroll
        for (int r = 0; r < 4; ++r) {
            float rm = fmaxf(fmaxf(sc[0][r], sc[1][r]), fmaxf(sc[2][r], sc[3][r]));
            rm = fmaxf(rm, __shfl_xor(rm, 1));
            rm = fmaxf(rm, __shfl_xor(rm, 2));
            rm = fmaxf(rm, __shfl_xor(rm, 4));
            rm = fmaxf(rm, __shfl_xor(rm, 8));
            float mnew = fmaxf(m[r], rm);
            float corr = __expf(m[r] - mnew);
            m[r] = mnew;
            int prow  = ((lane >> 4) << 2) + r;
            int rowsw = (prow & 7) << 4;
            float rs = 0.f;
#pragma unroll
            for (int c = 0; c < 4; ++c) {
                float p = __expf(sc[c][r] - mnew);
                rs += p;
                int colb = ((c << 4) + (lane & 15)) << 1;
                *(us*)(smem + PB + prow * 128 + (colb ^ rowsw)) = f2bf(p);
            }
            rs += __shfl_xor(rs, 1);
            rs += __shfl_xor(rs, 2);
            rs += __shfl_xor(rs, 4);
            rs += __shfl_xor(rs, 8);
            lsum[r] = lsum[r] * corr + rs;
#pragma unroll
            for (int db = 0; db < 4; ++db) oa[db][r] *= corr;
        }

        __builtin_amdgcn_s_setprio(1);
#pragma unroll
        for (int ks = 0; ks < 2; ++ks) {
            int prow = lane & 15;
            int poff = PB + prow * 128 + (((ks << 6) + ((lane >> 4) << 4)) ^ ((prow & 7) << 4));
            short8 pah = *(const short8*)(smem + poff);
#pragma unroll
            for (int db = 0; db < 4; ++db) {
                int vrow = (db << 4) + (lane & 15);
                int voff = vrow * 128 + (((ks << 6) + ((lane >> 4) << 4)) ^ ((vrow & 7) << 4));
                short8 vfh = *(const short8*)(smem + 16384 + voff);
                oa[db] = __builtin_amdgcn_mfma_f32_16x16x32_bf16(pah, vfh, oa[db], 0, 0, 0);
            }
        }
        __builtin_amdgcn_s_setprio(0);
        __syncthreads();
    }

    const int b = bh / NHEADS, h = bh - b * NHEADS;
#pragma unroll
    for (int r = 0; r < 4; ++r) {
        int q = q0 + (wv << 4) + ((lane >> 4) << 2) + r;
        if (q < NN) {
            float inv = 1.0f / lsum[r];
#pragma unroll
            for (int db = 0; db < 4; ++db) {
                int d = (db << 4) + (lane & 15);
                int dg = h * HD + d;
                float v = oa[db][r] * inv;
                size_t idx = (size_t)(b * NN + q) * CBS + (dg >> 5) * 64 + (dg & 31);
                us hb = f2bf(v);
                OC[idx]      = hb;
                OC[idx + 32] = f2bf(v - bf2f(hb));
            }
        }
    }
}

extern "C" void kernel_launch(void* const* d_in, const int* in_sizes, int n_in,
                              void* d_out, int out_size, void* d_ws, size_t ws_size,
                              hipStream_t stream) {
    const float* x      = (const float*)d_in[0];
    const float* qkv_w  = (const float*)d_in[1];
    const float* proj_w = (const float*)d_in[2];
    const float* proj_b = (const float*)d_in[3];
    const float* qnw    = (const float*)d_in[4];
    const float* knw    = (const float*)d_in[5];

    us* p = (us*)d_ws;
    us* Qhi = p;                 p += QSZ;
    us* Qlo = p;                 p += QSZ;
    us* Khi = p;                 p += QSZ;
    us* Klo = p;                 p += QSZ;
    us* Vth = p;                 p += VTSZ;
    us* XC  = p;                 p += (size_t)MM * CBS;     // combined X; reused as O
    us* WC  = p;                 p += (size_t)3 * CC * CBS; // qkv W^T combined
    us* PC  = p;                 p += (size_t)CC * CBS;     // proj W^T combined

    split_x<<<dim3((int)(((size_t)MM * CC) / 8 / 256)), 256, 0, stream>>>(x, XC);
    tsplit<<<dim3(3 * CC / 64, CC / 64), 256, 0, stream>>>(qkv_w, WC, 3 * CC);
    tsplit<<<dim3(CC / 64, CC / 64), 256, 0, stream>>>(proj_w, PC, CC);

    gemm_mfma<0><<<dim3(3 * CC / 128, (MM + 127) / 128), 256, 0, stream>>>(
        WC, XC, Qhi, Qlo, Khi, Klo, Vth, nullptr, nullptr);
    norm_rope<<<dim3(BB * NHEADS * NN / 4, 2), 256, 0, stream>>>(Qhi, Qlo, Khi, Klo, qnw, knw);
    attn_mfma<<<dim3(8 * 408), 256, 0, stream>>>(Qhi, Qlo, Khi, Klo, Vth, XC);
    gemm_mfma<1><<<dim3(CC / 128, (MM + 127) / 128), 256, 0, stream>>>(
        PC, XC, nullptr, nullptr, nullptr, nullptr, nullptr,
        (float*)d_out, proj_b);
}

// Round 10
// 517.484 us; speedup vs baseline: 1.5388x; 1.0724x over previous
//
#include <hip/hip_runtime.h>
#include <math.h>

#define NHEADS 12
#define HD 64
#define BB 16
#define NN 1025
#define CC 768
#define MM (BB * NN)                       // 16400
#define QSZ ((size_t)BB * NHEADS * NN * HD)   // 12,595,200
#define NNP 1032                           // padded t-stride for V^T
#define VTSZ ((size_t)BB * NHEADS * HD * NNP)
#define CBS 1536                           // combined-layout row stride (elems): [kblk][hi32|lo32]

typedef __attribute__((ext_vector_type(8))) short short8;
typedef __attribute__((ext_vector_type(4))) float f32x4;
typedef __attribute__((ext_vector_type(4))) unsigned short us4;
typedef unsigned short us;

typedef __attribute__((address_space(3))) unsigned int lds_u32;
typedef const __attribute__((address_space(1))) unsigned int g_u32;

__device__ __forceinline__ void gload16(const void* g, void* l) {
    __builtin_amdgcn_global_load_lds((g_u32*)g, (lds_u32*)l, 16, 0, 0);
}

__device__ __forceinline__ int imin(int a, int b) { return a < b ? a : b; }

__device__ __forceinline__ us f2bf(float f) {   // RTNE fp32->bf16 bits
    unsigned u = __float_as_uint(f);
    u += 0x7FFF + ((u >> 16) & 1);
    return (us)(u >> 16);
}
__device__ __forceinline__ float bf2f(us b) {
    return __uint_as_float(((unsigned)b) << 16);
}
__device__ __forceinline__ unsigned cvtpk(float a, float b) {   // low16=bf16(a), high16=bf16(b)
    unsigned r;
    asm("v_cvt_pk_bf16_f32 %0, %1, %2" : "=v"(r) : "v"(a), "v"(b));
    return r;
}

// ---------------- split_x: fp32 -> combined hi/lo layout [row][kblk][hi32|lo32] ----
__global__ __launch_bounds__(256) void split_x(const float* __restrict__ src,
                                               us* __restrict__ xc) {
    size_t gid = (size_t)blockIdx.x * 256 + threadIdx.x;
    size_t e = gid * 8;
    int row = (int)(e / CC), k = (int)(e % CC);
    float4 a = *(const float4*)(src + e);
    float4 b = *(const float4*)(src + e + 4);
    float v[8] = {a.x, a.y, a.z, a.w, b.x, b.y, b.z, b.w};
    short8 h, l;
#pragma unroll
    for (int j = 0; j < 8; ++j) {
        us hb = f2bf(v[j]);
        h[j] = (short)hb;
        l[j] = (short)f2bf(v[j] - bf2f(hb));
    }
    size_t o = (size_t)row * CBS + (k >> 5) * 64 + (k & 31);
    *(short8*)(xc + o)      = h;
    *(short8*)(xc + o + 32) = l;
}

// ---------------- tsplit: W [K][N] fp32 -> W^T combined [N][kblk][hi32|lo32] -------
__global__ __launch_bounds__(256) void tsplit(const float* __restrict__ w,
                                              us* __restrict__ wc, int N) {
    __shared__ float tile[64][65];
    const int t = threadIdx.x;
    const int n0 = blockIdx.x * 64, k0 = blockIdx.y * 64;
    {
        int kr = t & 63, so = t >> 6;
#pragma unroll
        for (int g = 0; g < 4; ++g) {
            int c = (so * 4 + g) * 4;
            float4 v = *(const float4*)(w + (size_t)(k0 + kr) * N + n0 + c);
            tile[kr][c + 0] = v.x; tile[kr][c + 1] = v.y;
            tile[kr][c + 2] = v.z; tile[kr][c + 3] = v.w;
        }
    }
    __syncthreads();
    int nr = t & 63, half = t >> 6;     // 16 consecutive k per thread
#pragma unroll
    for (int blk = 0; blk < 2; ++blk) {
        short8 h, l;
#pragma unroll
        for (int j = 0; j < 8; ++j) {
            float v = tile[half * 16 + blk * 8 + j][nr];
            us hb = f2bf(v);
            h[j] = (short)hb; l[j] = (short)f2bf(v - bf2f(hb));
        }
        int kg = k0 + half * 16 + blk * 8;
        size_t o = (size_t)(n0 + nr) * CBS + (kg >> 5) * 64 + (kg & 31);
        *(short8*)(wc + o)      = h;
        *(short8*)(wc + o + 32) = l;
    }
}

// ---------------- gemm_mfma: global_load_lds staging, pre-swizzled source ----------
template<int MODE>
__global__ __launch_bounds__(256) void gemm_mfma(
    const us* __restrict__ A,      // W^T combined [N][CBS]
    const us* __restrict__ B,      // X/O combined [M][CBS]
    us* __restrict__ Qhi, us* __restrict__ Qlo,
    us* __restrict__ Khi, us* __restrict__ Klo,
    us* __restrict__ Vth,
    float* __restrict__ fout, const float* __restrict__ bias) {
    __shared__ __align__(16) char lds[32768];
    char* ldsA = lds;
    char* ldsB = lds + 16384;
    const int tid = threadIdx.x;
    const int lane = tid & 63, wv = tid >> 6;
    const int wn = wv >> 1, wm = wv & 1;
    const int n0 = blockIdx.x * 128, m0 = blockIdx.y * 128;

    f32x4 acc[4][4];
    const f32x4 fz = {0.f, 0.f, 0.f, 0.f};
#pragma unroll
    for (int a = 0; a < 4; ++a)
#pragma unroll
        for (int b = 0; b < 4; ++b) acc[a][b] = fz;

    const int lrow = lane >> 3;
    const int c    = (lane & 7) ^ lrow;
    size_t aoff[4], boff[4];
#pragma unroll
    for (int i = 0; i < 4; ++i) {
        int ra = n0 + wv * 32 + i * 8 + lrow;
        int rb = imin(m0 + wv * 32 + i * 8 + lrow, MM - 1);
        aoff[i] = (size_t)ra * CBS + c * 8;
        boff[i] = (size_t)rb * CBS + c * 8;
    }

    for (int t = 0; t < CC / 32; ++t) {
        const size_t kb = (size_t)t * 64;
#pragma unroll
        for (int i = 0; i < 4; ++i) {
            gload16(A + aoff[i] + kb, ldsA + (wv * 32 + i * 8) * 128);
            gload16(B + boff[i] + kb, ldsB + (wv * 32 + i * 8) * 128);
        }
        __syncthreads();

        short8 af[4][2];
        const int ko = (lane >> 4) << 4;
#pragma unroll
        for (int nc = 0; nc < 4; ++nc) {
            int ra = wn * 64 + nc * 16 + (lane & 15);
            const char* pA = ldsA + ra * 128;
            int rs = (ra & 7) << 4;
            af[nc][0] = *(const short8*)(pA + (ko ^ rs));
            af[nc][1] = *(const short8*)(pA + ((64 + ko) ^ rs));
        }
        __builtin_amdgcn_s_setprio(1);
#pragma unroll
        for (int mc = 0; mc < 4; ++mc) {
            int rb = wm * 64 + mc * 16 + (lane & 15);
            const char* pB = ldsB + rb * 128;
            int rs = (rb & 7) << 4;
            short8 b0 = *(const short8*)(pB + (ko ^ rs));
            short8 b1 = *(const short8*)(pB + ((64 + ko) ^ rs));
#pragma unroll
            for (int nc = 0; nc < 4; ++nc) {
                acc[nc][mc] = __builtin_amdgcn_mfma_f32_16x16x32_bf16(af[nc][0], b0, acc[nc][mc], 0, 0, 0);
                acc[nc][mc] = __builtin_amdgcn_mfma_f32_16x16x32_bf16(af[nc][0], b1, acc[nc][mc], 0, 0, 0);
                acc[nc][mc] = __builtin_amdgcn_mfma_f32_16x16x32_bf16(af[nc][1], b0, acc[nc][mc], 0, 0, 0);
            }
        }
        __builtin_amdgcn_s_setprio(0);
        __syncthreads();
    }

#pragma unroll
    for (int mc = 0; mc < 4; ++mc) {
        int m = m0 + wm * 64 + mc * 16 + (lane & 15);
        if (m >= MM) continue;
        if (MODE == 0) {
            int b = m / NN, t = m - b * NN;
#pragma unroll
            for (int nc = 0; nc < 4; ++nc) {
                int n = n0 + wn * 64 + nc * 16 + ((lane >> 4) << 2);
                int s = n0 / CC;
                int nin = n - s * CC;
                int head = nin >> 6, d0 = nin & 63;
                int bh = b * NHEADS + head;
                if (s < 2) {
                    us4 h4, l4;
#pragma unroll
                    for (int r = 0; r < 4; ++r) {
                        float v = acc[nc][mc][r];
                        us hb = f2bf(v);
                        h4[r] = hb; l4[r] = f2bf(v - bf2f(hb));
                    }
                    size_t idx = ((size_t)bh * NN + t) * HD + d0;
                    if (s == 0) { *(us4*)(Qhi + idx) = h4; *(us4*)(Qlo + idx) = l4; }
                    else        { *(us4*)(Khi + idx) = h4; *(us4*)(Klo + idx) = l4; }
                } else {
#pragma unroll
                    for (int r = 0; r < 4; ++r) {
                        float v = acc[nc][mc][r];
                        size_t idx = ((size_t)bh * HD + d0 + r) * NNP + t;
                        Vth[idx] = f2bf(v);
                        if (t == NN - 1) {
#pragma unroll
                            for (int tt = 1; tt <= 7; ++tt) Vth[idx + tt] = 0;
                        }
                    }
                }
            }
        } else {
#pragma unroll
            for (int nc = 0; nc < 4; ++nc) {
                int n = n0 + wn * 64 + nc * 16 + ((lane >> 4) << 2);
                float4 o = {acc[nc][mc][0] + bias[n + 0], acc[nc][mc][1] + bias[n + 1],
                            acc[nc][mc][2] + bias[n + 2], acc[nc][mc][3] + bias[n + 3]};
                *(float4*)(fout + (size_t)m * CC + n) = o;
            }
        }
    }
}

// ---------------- norm_rope: fold 0.125*log2e into q (attn uses exp2) --------------
__global__ __launch_bounds__(256) void norm_rope(us* __restrict__ Qhi, us* __restrict__ Qlo,
                                                 us* __restrict__ Khi, us* __restrict__ Klo,
                                                 const float* __restrict__ qw,
                                                 const float* __restrict__ kw) {
    const int lane = threadIdx.x & 63;
    const int widx = threadIdx.x >> 6;
    const int rid  = blockIdx.x * 4 + widx;
    const bool isq = (blockIdx.y == 0);
    us* Ph = (isq ? Qhi : Khi);
    us* Pl = (isq ? Qlo : Klo);
    const float* w = isq ? qw : kw;
    const int t = rid % NN;
    size_t base = (size_t)rid * HD + lane;

    float v = bf2f(Ph[base]) + bf2f(Pl[base]);
    float ss = v * v;
#pragma unroll
    for (int o = 32; o; o >>= 1) ss += __shfl_xor(ss, o);
    float r = 1.0f / sqrtf(ss * (1.0f / 64.0f) + 1e-6f);
    v = v * r * w[lane];

    float partner = __shfl_xor(v, 32);
    if (t > 0) {
        int p   = t - 1;
        int pos = (lane < 32) ? (p & 31) : (p >> 5);
        int j   = lane & 15;
        float invf = exp2f((float)j * (-13.287712379549449f / 16.0f));
        float ang  = (float)pos * invf;
        float c = cosf(ang), sn = sinf(ang);
        float rh = (lane < 32) ? -partner : partner;
        v = v * c + rh * sn;
    }
    if (isq) v *= 0.125f * 1.4426950408889634f;   // d^-0.5 and log2(e) folded in
    us hb = f2bf(v);
    Ph[base] = hb;
    Pl[base] = f2bf(v - bf2f(hb));
}

// ---------------- attn: swapped-QK^T MFMA flash attention --------------------------
// mfma(K,Q): lane holds S[k=16c+4g+r][q=lane&15] -> per-lane row softmax,
// packed b64 P writes. PV and epilogue layouts unchanged.
__global__ __launch_bounds__(256, 4) void attn_mfma(
    const us* __restrict__ Qhi, const us* __restrict__ Qlo,
    const us* __restrict__ Khi, const us* __restrict__ Klo,
    const us* __restrict__ Vth,
    us* __restrict__ OC) {
    __shared__ __align__(16) char smem[32768];
    const int tid = threadIdx.x;
    const int lane = tid & 63, wv = tid >> 6;
    const int g = lane >> 4, q̂ = lane & 15;

    int lin = blockIdx.x;
    int xcd = lin & 7, loc = lin >> 3;
    int bh  = (loc / 17) * 8 + xcd;
    int qb  = loc - (loc / 17) * 17;
    const int q0 = qb * 64;

    const size_t kbase0 = (size_t)bh * NN * HD;
    const size_t vbase0 = (size_t)bh * HD * NNP;

    short8 qfh[2], qfl[2];
    {
        int qr = imin(q0 + (wv << 4) + q̂, NN - 1);
        const us* qp  = Qhi + kbase0 + (size_t)qr * HD + (g << 3);
        const us* qp2 = Qlo + kbase0 + (size_t)qr * HD + (g << 3);
        qfh[0] = *(const short8*)(qp);
        qfh[1] = *(const short8*)(qp + 32);
        qfl[0] = *(const short8*)(qp2);
        qfl[1] = *(const short8*)(qp2 + 32);
    }

    f32x4 oa[4];
    const f32x4 fz = {0.f, 0.f, 0.f, 0.f};
#pragma unroll
    for (int db = 0; db < 4; ++db) oa[db] = fz;
    float m_r = -INFINITY;   // running max for row q = lane&15 (log2 domain)
    float l_r = 0.f;         // running denom for row q

    const int PB = 24576 + wv * 2048;

    short8 pkh[2], pkl[2], pvh[2];
    const int srow = (wv << 4) + (lane >> 3);
    const int sg   = lane & 7;
    auto issue_loads = [&](int j0) {
#pragma unroll
        for (int i = 0; i < 2; ++i) {
            int row = srow + (i << 3);
            int krow = imin(j0 + row, NN - 1);
            pkh[i] = *(const short8*)(Khi + kbase0 + (size_t)krow * HD + (sg << 3));
            pkl[i] = *(const short8*)(Klo + kbase0 + (size_t)krow * HD + (sg << 3));
            int k0 = j0 + (sg << 3);
            if (k0 > 1024) k0 = 1024;
            pvh[i] = *(const short8*)(Vth + vbase0 + (size_t)row * NNP + k0);
        }
    };
    issue_loads(0);

    for (int t = 0; t < 17; ++t) {
        const int j0 = t * 64;
#pragma unroll
        for (int i = 0; i < 2; ++i) {
            int row = srow + (i << 3);
            int off = row * 128 + ((sg << 4) ^ ((row & 7) << 4));
            *(short8*)(smem + off)         = pkh[i];
            *(short8*)(smem + 8192 + off)  = pkl[i];
            *(short8*)(smem + 16384 + off) = pvh[i];
        }
        __syncthreads();
        if (t < 16) issue_loads(j0 + 64);

        // ---- S^T = K·Q (3 hi/lo products, swapped operands) ----
        f32x4 sc[4];
#pragma unroll
        for (int c = 0; c < 4; ++c) sc[c] = fz;
        __builtin_amdgcn_s_setprio(1);
#pragma unroll
        for (int ks = 0; ks < 2; ++ks) {
#pragma unroll
            for (int c = 0; c < 4; ++c) {
                int row  = (c << 4) + q̂;
                int boff = row * 128 + (((ks << 6) + (g << 4)) ^ ((row & 7) << 4));
                short8 kfh = *(const short8*)(smem + boff);
                short8 kfl = *(const short8*)(smem + 8192 + boff);
                sc[c] = __builtin_amdgcn_mfma_f32_16x16x32_bf16(kfh, qfh[ks], sc[c], 0, 0, 0);
                sc[c] = __builtin_amdgcn_mfma_f32_16x16x32_bf16(kfh, qfl[ks], sc[c], 0, 0, 0);
                sc[c] = __builtin_amdgcn_mfma_f32_16x16x32_bf16(kfl, qfh[ks], sc[c], 0, 0, 0);
            }
        }
        __builtin_amdgcn_s_setprio(0);

        // ---- mask tail keys (uniform branch: only last tile) ----
        if (j0 + 64 > NN) {
#pragma unroll
            for (int c = 0; c < 4; ++c)
#pragma unroll
                for (int r = 0; r < 4; ++r)
                    if (j0 + (c << 4) + (g << 2) + r >= NN) sc[c][r] = -1e30f;
        }

        // ---- per-lane row softmax (row q = lane&15, replicated over g) ----
        float rm = sc[0][0];
#pragma unroll
        for (int c = 0; c < 4; ++c)
#pragma unroll
            for (int r = 0; r < 4; ++r) rm = fmaxf(rm, sc[c][r]);
        rm = fmaxf(rm, __shfl_xor(rm, 16));
        rm = fmaxf(rm, __shfl_xor(rm, 32));
        float mnew = fmaxf(m_r, rm);
        float corr = exp2f(m_r - mnew);
        m_r = mnew;

        float p[4][4];
        float rs = 0.f;
#pragma unroll
        for (int c = 0; c < 4; ++c)
#pragma unroll
            for (int r = 0; r < 4; ++r) {
                p[c][r] = exp2f(sc[c][r] - mnew);
                rs += p[c][r];
            }
        rs += __shfl_xor(rs, 16);
        rs += __shfl_xor(rs, 32);
        l_r = l_r * corr + rs;

        // ---- pack P (bf16 pairs) and write 4x b64 into swizzled [q][k] layout ----
#pragma unroll
        for (int c = 0; c < 4; ++c) {
            uint2 w;
            w.x = cvtpk(p[c][0], p[c][1]);
            w.y = cvtpk(p[c][2], p[c][3]);
            int off = PB + q̂ * 128 + ((((c << 1) + (g >> 1)) << 4) ^ ((q̂ & 7) << 4)) + ((g & 1) << 3);
            *(uint2*)(smem + off) = w;
        }

        // ---- rescale O accumulator (corr of row q' = 4g+r via bpermute) ----
#pragma unroll
        for (int r = 0; r < 4; ++r) {
            float cr = __shfl(corr, (g << 2) + r);
#pragma unroll
            for (int db = 0; db < 4; ++db) oa[db][r] *= cr;
        }

        // ---- O += P·V (unchanged) ----
        __builtin_amdgcn_s_setprio(1);
#pragma unroll
        for (int ks = 0; ks < 2; ++ks) {
            int poff = PB + q̂ * 128 + (((ks << 6) + (g << 4)) ^ ((q̂ & 7) << 4));
            short8 pah = *(const short8*)(smem + poff);
#pragma unroll
            for (int db = 0; db < 4; ++db) {
                int vrow = (db << 4) + q̂;
                int voff = vrow * 128 + (((ks << 6) + (g << 4)) ^ ((vrow & 7) << 4));
                short8 vfh = *(const short8*)(smem + 16384 + voff);
                oa[db] = __builtin_amdgcn_mfma_f32_16x16x32_bf16(pah, vfh, oa[db], 0, 0, 0);
            }
        }
        __builtin_amdgcn_s_setprio(0);
        __syncthreads();
    }

    const int b = bh / NHEADS, h = bh - b * NHEADS;
#pragma unroll
    for (int r = 0; r < 4; ++r) {
        int q = q0 + (wv << 4) + (g << 2) + r;
        float linv = 1.0f / __shfl(l_r, (g << 2) + r);
        if (q < NN) {
#pragma unroll
            for (int db = 0; db < 4; ++db) {
                int d = (db << 4) + q̂;
                int dg = h * HD + d;
                float v = oa[db][r] * linv;
                size_t idx = (size_t)(b * NN + q) * CBS + (dg >> 5) * 64 + (dg & 31);
                us hb = f2bf(v);
                OC[idx]      = hb;
                OC[idx + 32] = f2bf(v - bf2f(hb));
            }
        }
    }
}

extern "C" void kernel_launch(void* const* d_in, const int* in_sizes, int n_in,
                              void* d_out, int out_size, void* d_ws, size_t ws_size,
                              hipStream_t stream) {
    const float* x      = (const float*)d_in[0];
    const float* qkv_w  = (const float*)d_in[1];
    const float* proj_w = (const float*)d_in[2];
    const float* proj_b = (const float*)d_in[3];
    const float* qnw    = (const float*)d_in[4];
    const float* knw    = (const float*)d_in[5];

    us* p = (us*)d_ws;
    us* Qhi = p;                 p += QSZ;
    us* Qlo = p;                 p += QSZ;
    us* Khi = p;                 p += QSZ;
    us* Klo = p;                 p += QSZ;
    us* Vth = p;                 p += VTSZ;
    us* XC  = p;                 p += (size_t)MM * CBS;     // combined X; reused as O
    us* WC  = p;                 p += (size_t)3 * CC * CBS; // qkv W^T combined
    us* PC  = p;                 p += (size_t)CC * CBS;     // proj W^T combined

    split_x<<<dim3((int)(((size_t)MM * CC) / 8 / 256)), 256, 0, stream>>>(x, XC);
    tsplit<<<dim3(3 * CC / 64, CC / 64), 256, 0, stream>>>(qkv_w, WC, 3 * CC);
    tsplit<<<dim3(CC / 64, CC / 64), 256, 0, stream>>>(proj_w, PC, CC);

    gemm_mfma<0><<<dim3(3 * CC / 128, (MM + 127) / 128), 256, 0, stream>>>(
        WC, XC, Qhi, Qlo, Khi, Klo, Vth, nullptr, nullptr);
    norm_rope<<<dim3(BB * NHEADS * NN / 4, 2), 256, 0, stream>>>(Qhi, Qlo, Khi, Klo, qnw, knw);
    attn_mfma<<<dim3(8 * 408), 256, 0, stream>>>(Qhi, Qlo, Khi, Klo, Vth, XC);
    gemm_mfma<1><<<dim3(CC / 128, (MM + 127) / 128), 256, 0, stream>>>(
        PC, XC, nullptr, nullptr, nullptr, nullptr, nullptr,
        (float*)d_out, proj_b);
}

// Round 12
// 444.707 us; speedup vs baseline: 1.7906x; 1.1637x over previous
//
#include <hip/hip_runtime.h>
#include <math.h>

#define NHEADS 12
#define HD 64
#define BB 16
#define NN 1025
#define CC 768
#define MM (BB * NN)                       // 16400
#define QSZ ((size_t)BB * NHEADS * NN * HD)   // 12,595,200
#define NNP 1032                           // padded t-stride for V^T
#define VTSZ ((size_t)BB * NHEADS * HD * NNP)
#define CBS 1536                           // W^T combined row stride (elems): [kblk32][hi32|lo32]

typedef __attribute__((ext_vector_type(8))) short short8;
typedef __attribute__((ext_vector_type(4))) float f32x4;
typedef __attribute__((ext_vector_type(4))) unsigned short us4;
typedef __attribute__((ext_vector_type(2))) _Float16 h2v;
typedef unsigned short us;

typedef __attribute__((address_space(3))) unsigned int lds_u32;
typedef const __attribute__((address_space(1))) unsigned int g_u32;

__device__ __forceinline__ void gload16(const void* g, void* l) {
    __builtin_amdgcn_global_load_lds((g_u32*)g, (lds_u32*)l, 16, 0, 0);
}

__device__ __forceinline__ int imin(int a, int b) { return a < b ? a : b; }

__device__ __forceinline__ us f2h(float f) {          // fp32 -> fp16 bits (RTE)
    _Float16 h = (_Float16)f;
    return __builtin_bit_cast(unsigned short, h);
}
__device__ __forceinline__ float h2f(us b) {
    return (float)__builtin_bit_cast(_Float16, b);
}
__device__ __forceinline__ unsigned pkrtz(float a, float b) {  // 2xfp16 packed
    return __builtin_bit_cast(unsigned, __builtin_amdgcn_cvt_pkrtz(a, b));
}

// ---------------- split_x: fp32 -> plain fp16 [M][768] -----------------------------
__global__ __launch_bounds__(256) void split_x(const float* __restrict__ src,
                                               us* __restrict__ xc) {
    size_t e = ((size_t)blockIdx.x * 256 + threadIdx.x) * 8;
    float4 a = *(const float4*)(src + e);
    float4 b = *(const float4*)(src + e + 4);
    float v[8] = {a.x, a.y, a.z, a.w, b.x, b.y, b.z, b.w};
    short8 h;
#pragma unroll
    for (int j = 0; j < 8; ++j) h[j] = (short)f2h(v[j]);
    *(short8*)(xc + e) = h;
}

// ---------------- tsplit: W [K][N] fp32 -> W^T combined fp16 [N][kblk][hi32|lo32] --
__global__ __launch_bounds__(256) void tsplit(const float* __restrict__ w,
                                              us* __restrict__ wc, int N) {
    __shared__ float tile[64][65];
    const int t = threadIdx.x;
    const int n0 = blockIdx.x * 64, k0 = blockIdx.y * 64;
    {
        int kr = t & 63, so = t >> 6;
#pragma unroll
        for (int g = 0; g < 4; ++g) {
            int c = (so * 4 + g) * 4;
            float4 v = *(const float4*)(w + (size_t)(k0 + kr) * N + n0 + c);
            tile[kr][c + 0] = v.x; tile[kr][c + 1] = v.y;
            tile[kr][c + 2] = v.z; tile[kr][c + 3] = v.w;
        }
    }
    __syncthreads();
    int nr = t & 63, half = t >> 6;     // 16 consecutive k per thread
#pragma unroll
    for (int blk = 0; blk < 2; ++blk) {
        short8 h, l;
#pragma unroll
        for (int j = 0; j < 8; ++j) {
            float v = tile[half * 16 + blk * 8 + j][nr];
            us hb = f2h(v);
            h[j] = (short)hb; l[j] = (short)f2h(v - h2f(hb));
        }
        int kg = k0 + half * 16 + blk * 8;
        size_t o = (size_t)(n0 + nr) * CBS + (kg >> 5) * 64 + (kg & 31);
        *(short8*)(wc + o)      = h;
        *(short8*)(wc + o + 32) = l;
    }
}

// ---------------- gemm_mfma: fp16 2-product, BK=64, gload_lds, swizzled ------------
// LDS: A 128 rows x 256B ([k0-31 hi|lo][k32-63 hi|lo], 16 slots, s^(row&15));
//      B 128 rows x 128B (64 k hi-only, 8 slots, s^(row&7)).
template<int MODE>
__global__ __launch_bounds__(256) void gemm_mfma(
    const us* __restrict__ A,      // W^T combined [N][CBS]
    const us* __restrict__ B,      // X/O plain fp16 [M][768]
    us* __restrict__ Qhi, us* __restrict__ Qlo,
    us* __restrict__ Khi, us* __restrict__ Klo,
    us* __restrict__ Vth,
    float* __restrict__ fout, const float* __restrict__ bias) {
    __shared__ __align__(16) char lds[49152];
    char* ldsA = lds;              // 32 KB
    char* ldsB = lds + 32768;      // 16 KB
    const int tid = threadIdx.x;
    const int lane = tid & 63, wv = tid >> 6;
    const int wn = wv >> 1, wm = wv & 1;
    const int n0 = blockIdx.x * 128, m0 = blockIdx.y * 128;

    f32x4 acc[4][4];
    const f32x4 fz = {0.f, 0.f, 0.f, 0.f};
#pragma unroll
    for (int a = 0; a < 4; ++a)
#pragma unroll
        for (int b = 0; b < 4; ++b) acc[a][b] = fz;

    // A staging: iter i -> row = i*16 + wv*4 + (lane>>4), slot = lane&15,
    // source chunk = slot ^ (row&15)  (row&15 is i-invariant)
    const int arow0 = (wv << 2) + (lane >> 4);
    const int ca    = (lane & 15) ^ (arow0 & 15);
    const size_t abase = (size_t)(n0 + arow0) * CBS + ca * 8;
    // B staging: iter i -> row = i*32 + wv*8 + (lane>>3), slot = lane&7,
    // source chunk = slot ^ ((lane>>3)&7)
    const int brow0 = (wv << 3) + (lane >> 3);
    const int cb    = (lane & 7) ^ ((lane >> 3) & 7);
    size_t boff[4];
#pragma unroll
    for (int i = 0; i < 4; ++i)
        boff[i] = (size_t)imin(m0 + brow0 + i * 32, MM - 1) * CC + cb * 8;

    const int wdst = wv * 1024;

    for (int t = 0; t < CC / 64; ++t) {
#pragma unroll
        for (int i = 0; i < 8; ++i)
            gload16(A + abase + (size_t)i * 16 * CBS + t * 128, ldsA + i * 4096 + wdst);
#pragma unroll
        for (int i = 0; i < 4; ++i)
            gload16(B + boff[i] + t * 64, ldsB + i * 4096 + wdst);
        __syncthreads();   // drains vmcnt -> tile valid

        const int j  = lane >> 4;
        const int rl = lane & 15;
#pragma unroll
        for (int kh = 0; kh < 2; ++kh) {
            short8 ah[4], al[4];
#pragma unroll
            for (int nc = 0; nc < 4; ++nc) {
                int ra = wn * 64 + nc * 16 + rl;
                const char* pA = ldsA + ra * 256;
                int x = ra & 15;
                ah[nc] = *(const short8*)(pA + ((((kh << 3) + j) ^ x) << 4));
                al[nc] = *(const short8*)(pA + ((((kh << 3) + 4 + j) ^ x) << 4));
            }
            __builtin_amdgcn_s_setprio(1);
#pragma unroll
            for (int mc = 0; mc < 4; ++mc) {
                int rb = wm * 64 + mc * 16 + rl;
                int sb = ((kh << 2) + j) ^ (rb & 7);
                short8 bf = *(const short8*)(ldsB + rb * 128 + (sb << 4));
#pragma unroll
                for (int nc = 0; nc < 4; ++nc) {
                    acc[nc][mc] = __builtin_amdgcn_mfma_f32_16x16x32_f16(ah[nc], bf, acc[nc][mc], 0, 0, 0);
                    acc[nc][mc] = __builtin_amdgcn_mfma_f32_16x16x32_f16(al[nc], bf, acc[nc][mc], 0, 0, 0);
                }
            }
            __builtin_amdgcn_s_setprio(0);
        }
        __syncthreads();
    }

#pragma unroll
    for (int mc = 0; mc < 4; ++mc) {
        int m = m0 + wm * 64 + mc * 16 + (lane & 15);
        if (m >= MM) continue;
        if (MODE == 0) {
            int b = m / NN, t = m - b * NN;
#pragma unroll
            for (int nc = 0; nc < 4; ++nc) {
                int n = n0 + wn * 64 + nc * 16 + ((lane >> 4) << 2);
                int s = n0 / CC;
                int nin = n - s * CC;
                int head = nin >> 6, d0 = nin & 63;
                int bh = b * NHEADS + head;
                if (s < 2) {
                    us4 h4, l4;
#pragma unroll
                    for (int r = 0; r < 4; ++r) {
                        float v = acc[nc][mc][r];
                        us hb = f2h(v);
                        h4[r] = hb; l4[r] = f2h(v - h2f(hb));
                    }
                    size_t idx = ((size_t)bh * NN + t) * HD + d0;
                    if (s == 0) { *(us4*)(Qhi + idx) = h4; *(us4*)(Qlo + idx) = l4; }
                    else        { *(us4*)(Khi + idx) = h4; *(us4*)(Klo + idx) = l4; }
                } else {
#pragma unroll
                    for (int r = 0; r < 4; ++r) {
                        float v = acc[nc][mc][r];
                        size_t idx = ((size_t)bh * HD + d0 + r) * NNP + t;
                        Vth[idx] = f2h(v);
                        if (t == NN - 1) {
#pragma unroll
                            for (int tt = 1; tt <= 7; ++tt) Vth[idx + tt] = 0;
                        }
                    }
                }
            }
        } else {
#pragma unroll
            for (int nc = 0; nc < 4; ++nc) {
                int n = n0 + wn * 64 + nc * 16 + ((lane >> 4) << 2);
                float4 o = {acc[nc][mc][0] + bias[n + 0], acc[nc][mc][1] + bias[n + 1],
                            acc[nc][mc][2] + bias[n + 2], acc[nc][mc][3] + bias[n + 3]};
                *(float4*)(fout + (size_t)m * CC + n) = o;
            }
        }
    }
}

// ---------------- norm_rope: fp16 hi/lo planes; fold 0.125*log2e into q ------------
__global__ __launch_bounds__(256) void norm_rope(us* __restrict__ Qhi, us* __restrict__ Qlo,
                                                 us* __restrict__ Khi, us* __restrict__ Klo,
                                                 const float* __restrict__ qw,
                                                 const float* __restrict__ kw) {
    const int lane = threadIdx.x & 63;
    const int widx = threadIdx.x >> 6;
    const int rid  = blockIdx.x * 4 + widx;
    const bool isq = (blockIdx.y == 0);
    us* Ph = (isq ? Qhi : Khi);
    us* Pl = (isq ? Qlo : Klo);
    const float* w = isq ? qw : kw;
    const int t = rid % NN;
    size_t base = (size_t)rid * HD + lane;

    float v = h2f(Ph[base]) + h2f(Pl[base]);
    float ss = v * v;
#pragma unroll
    for (int o = 32; o; o >>= 1) ss += __shfl_xor(ss, o);
    float r = 1.0f / sqrtf(ss * (1.0f / 64.0f) + 1e-6f);
    v = v * r * w[lane];

    float partner = __shfl_xor(v, 32);
    if (t > 0) {
        int p   = t - 1;
        int pos = (lane < 32) ? (p & 31) : (p >> 5);
        int j   = lane & 15;
        float invf = exp2f((float)j * (-13.287712379549449f / 16.0f));
        float ang  = (float)pos * invf;
        float c = cosf(ang), sn = sinf(ang);
        float rh = (lane < 32) ? -partner : partner;
        v = v * c + rh * sn;
    }
    if (isq) v *= 0.125f * 1.4426950408889634f;   // d^-0.5 and log2(e)
    us hb = f2h(v);
    Ph[base] = hb;
    Pl[base] = f2h(v - h2f(hb));
}

// ---------------- attn: swapped-QK^T fp16 MFMA flash attention ---------------------
__global__ __launch_bounds__(256, 4) void attn_mfma(
    const us* __restrict__ Qhi, const us* __restrict__ Qlo,
    const us* __restrict__ Khi, const us* __restrict__ Klo,
    const us* __restrict__ Vth,
    us* __restrict__ OC) {
    __shared__ __align__(16) char smem[32768];
    const int tid = threadIdx.x;
    const int lane = tid & 63, wv = tid >> 6;
    const int g = lane >> 4, qi = lane & 15;

    int lin = blockIdx.x;
    int xcd = lin & 7, loc = lin >> 3;
    int bh  = (loc / 17) * 8 + xcd;
    int qb  = loc - (loc / 17) * 17;
    const int q0 = qb * 64;

    const size_t kbase0 = (size_t)bh * NN * HD;
    const size_t vbase0 = (size_t)bh * HD * NNP;

    short8 qfh[2], qfl[2];
    {
        int qr = imin(q0 + (wv << 4) + qi, NN - 1);
        const us* qp  = Qhi + kbase0 + (size_t)qr * HD + (g << 3);
        const us* qp2 = Qlo + kbase0 + (size_t)qr * HD + (g << 3);
        qfh[0] = *(const short8*)(qp);
        qfh[1] = *(const short8*)(qp + 32);
        qfl[0] = *(const short8*)(qp2);
        qfl[1] = *(const short8*)(qp2 + 32);
    }

    f32x4 oa[4];
    const f32x4 fz = {0.f, 0.f, 0.f, 0.f};
#pragma unroll
    for (int db = 0; db < 4; ++db) oa[db] = fz;
    float m_r = -INFINITY;
    float l_r = 0.f;

    const int PB = 24576 + wv * 2048;

    short8 pkh[2], pkl[2], pvh[2];
    const int srow = (wv << 4) + (lane >> 3);
    const int sg   = lane & 7;
    auto issue_loads = [&](int j0) {
#pragma unroll
        for (int i = 0; i < 2; ++i) {
            int row = srow + (i << 3);
            int krow = imin(j0 + row, NN - 1);
            pkh[i] = *(const short8*)(Khi + kbase0 + (size_t)krow * HD + (sg << 3));
            pkl[i] = *(const short8*)(Klo + kbase0 + (size_t)krow * HD + (sg << 3));
            int k0 = j0 + (sg << 3);
            if (k0 > 1024) k0 = 1024;
            pvh[i] = *(const short8*)(Vth + vbase0 + (size_t)row * NNP + k0);
        }
    };
    issue_loads(0);

    for (int t = 0; t < 17; ++t) {
        const int j0 = t * 64;
#pragma unroll
        for (int i = 0; i < 2; ++i) {
            int row = srow + (i << 3);
            int off = row * 128 + ((sg << 4) ^ ((row & 7) << 4));
            *(short8*)(smem + off)         = pkh[i];
            *(short8*)(smem + 8192 + off)  = pkl[i];
            *(short8*)(smem + 16384 + off) = pvh[i];
        }
        __syncthreads();
        if (t < 16) issue_loads(j0 + 64);

        // S^T = K·Q (3 fp16 hi/lo products, swapped operands)
        f32x4 sc[4];
#pragma unroll
        for (int c = 0; c < 4; ++c) sc[c] = fz;
        __builtin_amdgcn_s_setprio(1);
#pragma unroll
        for (int ks = 0; ks < 2; ++ks) {
#pragma unroll
            for (int c = 0; c < 4; ++c) {
                int row  = (c << 4) + qi;
                int boff = row * 128 + (((ks << 6) + (g << 4)) ^ ((row & 7) << 4));
                short8 kfh = *(const short8*)(smem + boff);
                short8 kfl = *(const short8*)(smem + 8192 + boff);
                sc[c] = __builtin_amdgcn_mfma_f32_16x16x32_f16(kfh, qfh[ks], sc[c], 0, 0, 0);
                sc[c] = __builtin_amdgcn_mfma_f32_16x16x32_f16(kfh, qfl[ks], sc[c], 0, 0, 0);
                sc[c] = __builtin_amdgcn_mfma_f32_16x16x32_f16(kfl, qfh[ks], sc[c], 0, 0, 0);
            }
        }
        __builtin_amdgcn_s_setprio(0);

        if (j0 + 64 > NN) {
#pragma unroll
            for (int c = 0; c < 4; ++c)
#pragma unroll
                for (int r = 0; r < 4; ++r)
                    if (j0 + (c << 4) + (g << 2) + r >= NN) sc[c][r] = -1e30f;
        }

        // per-lane row softmax (row q = lane&15, replicated over g)
        float rm = sc[0][0];
#pragma unroll
        for (int c = 0; c < 4; ++c)
#pragma unroll
            for (int r = 0; r < 4; ++r) rm = fmaxf(rm, sc[c][r]);
        rm = fmaxf(rm, __shfl_xor(rm, 16));
        rm = fmaxf(rm, __shfl_xor(rm, 32));
        float mnew = fmaxf(m_r, rm);
        float corr = exp2f(m_r - mnew);
        m_r = mnew;

        float p[4][4];
        float rs = 0.f;
#pragma unroll
        for (int c = 0; c < 4; ++c)
#pragma unroll
            for (int r = 0; r < 4; ++r) {
                p[c][r] = exp2f(sc[c][r] - mnew);
                rs += p[c][r];
            }
        rs += __shfl_xor(rs, 16);
        rs += __shfl_xor(rs, 32);
        l_r = l_r * corr + rs;

        // pack P (fp16 pairs) and write 4x b64 into swizzled [q][k] layout
#pragma unroll
        for (int c = 0; c < 4; ++c) {
            uint2 w;
            w.x = pkrtz(p[c][0], p[c][1]);
            w.y = pkrtz(p[c][2], p[c][3]);
            int off = PB + qi * 128 + ((((c << 1) + (g >> 1)) << 4) ^ ((qi & 7) << 4)) + ((g & 1) << 3);
            *(uint2*)(smem + off) = w;
        }

        // rescale O accumulator
#pragma unroll
        for (int r = 0; r < 4; ++r) {
            float cr = __shfl(corr, (g << 2) + r);
#pragma unroll
            for (int db = 0; db < 4; ++db) oa[db][r] *= cr;
        }

        // O += P·V (single fp16 product)
        __builtin_amdgcn_s_setprio(1);
#pragma unroll
        for (int ks = 0; ks < 2; ++ks) {
            int poff = PB + qi * 128 + (((ks << 6) + (g << 4)) ^ ((qi & 7) << 4));
            short8 pah = *(const short8*)(smem + poff);
#pragma unroll
            for (int db = 0; db < 4; ++db) {
                int vrow = (db << 4) + qi;
                int voff = vrow * 128 + (((ks << 6) + (g << 4)) ^ ((vrow & 7) << 4));
                short8 vfh = *(const short8*)(smem + 16384 + voff);
                oa[db] = __builtin_amdgcn_mfma_f32_16x16x32_f16(pah, vfh, oa[db], 0, 0, 0);
            }
        }
        __builtin_amdgcn_s_setprio(0);
        __syncthreads();
    }

    const int b = bh / NHEADS, h = bh - b * NHEADS;
#pragma unroll
    for (int r = 0; r < 4; ++r) {
        int q = q0 + (wv << 4) + (g << 2) + r;
        float linv = 1.0f / __shfl(l_r, (g << 2) + r);
        if (q < NN) {
#pragma unroll
            for (int db = 0; db < 4; ++db) {
                int d = (db << 4) + qi;
                int dg = h * HD + d;
                float v = oa[db][r] * linv;
                OC[(size_t)(b * NN + q) * CC + dg] = f2h(v);
            }
        }
    }
}

extern "C" void kernel_launch(void* const* d_in, const int* in_sizes, int n_in,
                              void* d_out, int out_size, void* d_ws, size_t ws_size,
                              hipStream_t stream) {
    const float* x      = (const float*)d_in[0];
    const float* qkv_w  = (const float*)d_in[1];
    const float* proj_w = (const float*)d_in[2];
    const float* proj_b = (const float*)d_in[3];
    const float* qnw    = (const float*)d_in[4];
    const float* knw    = (const float*)d_in[5];

    us* p = (us*)d_ws;
    us* Qhi = p;                 p += QSZ;
    us* Qlo = p;                 p += QSZ;
    us* Khi = p;                 p += QSZ;
    us* Klo = p;                 p += QSZ;
    us* Vth = p;                 p += VTSZ;
    us* XC  = p;                 p += (size_t)MM * CC;      // plain fp16 X; reused as O
    us* WC  = p;                 p += (size_t)3 * CC * CBS; // qkv W^T combined
    us* PC  = p;                 p += (size_t)CC * CBS;     // proj W^T combined

    split_x<<<dim3((int)(((size_t)MM * CC) / 8 / 256)), 256, 0, stream>>>(x, XC);
    tsplit<<<dim3(3 * CC / 64, CC / 64), 256, 0, stream>>>(qkv_w, WC, 3 * CC);
    tsplit<<<dim3(CC / 64, CC / 64), 256, 0, stream>>>(proj_w, PC, CC);

    gemm_mfma<0><<<dim3(3 * CC / 128, (MM + 127) / 128), 256, 0, stream>>>(
        WC, XC, Qhi, Qlo, Khi, Klo, Vth, nullptr, nullptr);
    norm_rope<<<dim3(BB * NHEADS * NN / 4, 2), 256, 0, stream>>>(Qhi, Qlo, Khi, Klo, qnw, knw);
    attn_mfma<<<dim3(8 * 408), 256, 0, stream>>>(Qhi, Qlo, Khi, Klo, Vth, XC);
    gemm_mfma<1><<<dim3(CC / 128, (MM + 127) / 128), 256, 0, stream>>>(
        PC, XC, nullptr, nullptr, nullptr, nullptr, nullptr,
        (float*)d_out, proj_b);
}

// Round 13
// 332.259 us; speedup vs baseline: 2.3966x; 1.3384x over previous
//
#include <hip/hip_runtime.h>
#include <math.h>

#define NHEADS 12
#define HD 64
#define BB 16
#define NN 1025
#define CC 768
#define MM (BB * NN)                       // 16400
#define QSZ ((size_t)BB * NHEADS * NN * HD)   // 12,595,200
#define NNP 1032                           // padded t-stride for V^T
#define VTSZ ((size_t)BB * NHEADS * HD * NNP)

typedef __attribute__((ext_vector_type(8))) short short8;
typedef __attribute__((ext_vector_type(4))) float f32x4;
typedef __attribute__((ext_vector_type(4))) unsigned short us4;
typedef unsigned short us;

typedef __attribute__((address_space(3))) unsigned int lds_u32;
typedef const __attribute__((address_space(1))) unsigned int g_u32;

__device__ __forceinline__ void gload16(const void* g, void* l) {
    __builtin_amdgcn_global_load_lds((g_u32*)g, (lds_u32*)l, 16, 0, 0);
}

__device__ __forceinline__ int imin(int a, int b) { return a < b ? a : b; }

__device__ __forceinline__ us f2h(float f) {          // fp32 -> fp16 bits (RTE)
    _Float16 h = (_Float16)f;
    return __builtin_bit_cast(unsigned short, h);
}
__device__ __forceinline__ float h2f(us b) {
    return (float)__builtin_bit_cast(_Float16, b);
}
__device__ __forceinline__ unsigned pkrtz(float a, float b) {  // 2xfp16 packed
    return __builtin_bit_cast(unsigned, __builtin_amdgcn_cvt_pkrtz(a, b));
}

// ---------------- split_x: fp32 -> plain fp16 [M][768] -----------------------------
__global__ __launch_bounds__(256) void split_x(const float* __restrict__ src,
                                               us* __restrict__ xc) {
    size_t e = ((size_t)blockIdx.x * 256 + threadIdx.x) * 8;
    float4 a = *(const float4*)(src + e);
    float4 b = *(const float4*)(src + e + 4);
    float v[8] = {a.x, a.y, a.z, a.w, b.x, b.y, b.z, b.w};
    short8 h;
#pragma unroll
    for (int j = 0; j < 8; ++j) h[j] = (short)f2h(v[j]);
    *(short8*)(xc + e) = h;
}

// ---------------- tsplit: W [K][N] fp32 -> W^T plain fp16 [N][K] -------------------
__global__ __launch_bounds__(256) void tsplit(const float* __restrict__ w,
                                              us* __restrict__ wc, int N) {
    __shared__ float tile[64][65];
    const int t = threadIdx.x;
    const int n0 = blockIdx.x * 64, k0 = blockIdx.y * 64;
    {
        int kr = t & 63, so = t >> 6;
#pragma unroll
        for (int g = 0; g < 4; ++g) {
            int c = (so * 4 + g) * 4;
            float4 v = *(const float4*)(w + (size_t)(k0 + kr) * N + n0 + c);
            tile[kr][c + 0] = v.x; tile[kr][c + 1] = v.y;
            tile[kr][c + 2] = v.z; tile[kr][c + 3] = v.w;
        }
    }
    __syncthreads();
    int nr = t & 63, half = t >> 6;     // 16 consecutive k per thread
    short8 h0, h1;
#pragma unroll
    for (int j = 0; j < 8; ++j) h0[j] = (short)f2h(tile[half * 16 + j][nr]);
#pragma unroll
    for (int j = 0; j < 8; ++j) h1[j] = (short)f2h(tile[half * 16 + 8 + j][nr]);
    size_t o = (size_t)(n0 + nr) * CC + k0 + half * 16;
    *(short8*)(wc + o)     = h0;
    *(short8*)(wc + o + 8) = h1;
}

// ---------------- gemm_mfma: plain fp16 single-product, BK=64, gload_lds -----------
// A/B LDS: 128 rows x 128B (8 slots of 16B, slot s holds chunk s^(row&7)).
template<int MODE>
__global__ __launch_bounds__(256) void gemm_mfma(
    const us* __restrict__ A,      // W^T plain fp16 [N][768]
    const us* __restrict__ B,      // X/O plain fp16 [M][768]
    us* __restrict__ Q, us* __restrict__ K, us* __restrict__ Vth,
    float* __restrict__ fout, const float* __restrict__ bias) {
    __shared__ __align__(16) char lds[32768];
    char* ldsA = lds;              // 16 KB
    char* ldsB = lds + 16384;      // 16 KB
    const int tid = threadIdx.x;
    const int lane = tid & 63, wv = tid >> 6;
    const int wn = wv >> 1, wm = wv & 1;
    const int n0 = blockIdx.x * 128, m0 = blockIdx.y * 128;

    f32x4 acc[4][4];
    const f32x4 fz = {0.f, 0.f, 0.f, 0.f};
#pragma unroll
    for (int a = 0; a < 4; ++a)
#pragma unroll
        for (int b = 0; b < 4; ++b) acc[a][b] = fz;

    // staging: iter i -> row = i*32 + wv*8 + (lane>>3), slot = lane&7,
    // source chunk = slot ^ ((lane>>3)&7)   (i-invariant: i*32, wv*8 ≡ 0 mod 8)
    const int srow = (wv << 3) + (lane >> 3);
    const int cb   = (lane & 7) ^ ((lane >> 3) & 7);
    size_t aoff[4], boff[4];
#pragma unroll
    for (int i = 0; i < 4; ++i) {
        aoff[i] = (size_t)(n0 + srow + i * 32) * CC + cb * 8;
        boff[i] = (size_t)imin(m0 + srow + i * 32, MM - 1) * CC + cb * 8;
    }
    const int wdst = wv * 1024;

    for (int t = 0; t < CC / 64; ++t) {
#pragma unroll
        for (int i = 0; i < 4; ++i) {
            gload16(A + aoff[i] + t * 64, ldsA + i * 4096 + wdst);
            gload16(B + boff[i] + t * 64, ldsB + i * 4096 + wdst);
        }
        __syncthreads();   // drains vmcnt -> tile valid

        const int j  = lane >> 4;
        const int rl = lane & 15;
#pragma unroll
        for (int kh = 0; kh < 2; ++kh) {
            short8 af[4];
#pragma unroll
            for (int nc = 0; nc < 4; ++nc) {
                int ra = wn * 64 + nc * 16 + rl;
                af[nc] = *(const short8*)(ldsA + ra * 128 + ((((kh << 2) + j) ^ (ra & 7)) << 4));
            }
            __builtin_amdgcn_s_setprio(1);
#pragma unroll
            for (int mc = 0; mc < 4; ++mc) {
                int rb = wm * 64 + mc * 16 + rl;
                short8 bf = *(const short8*)(ldsB + rb * 128 + ((((kh << 2) + j) ^ (rb & 7)) << 4));
#pragma unroll
                for (int nc = 0; nc < 4; ++nc)
                    acc[nc][mc] = __builtin_amdgcn_mfma_f32_16x16x32_f16(af[nc], bf, acc[nc][mc], 0, 0, 0);
            }
            __builtin_amdgcn_s_setprio(0);
        }
        __syncthreads();
    }

#pragma unroll
    for (int mc = 0; mc < 4; ++mc) {
        int m = m0 + wm * 64 + mc * 16 + (lane & 15);
        if (m >= MM) continue;
        if (MODE == 0) {
            int b = m / NN, t = m - b * NN;
#pragma unroll
            for (int nc = 0; nc < 4; ++nc) {
                int n = n0 + wn * 64 + nc * 16 + ((lane >> 4) << 2);
                int s = n0 / CC;
                int nin = n - s * CC;
                int head = nin >> 6, d0 = nin & 63;
                int bh = b * NHEADS + head;
                if (s < 2) {
                    us4 h4;
#pragma unroll
                    for (int r = 0; r < 4; ++r) h4[r] = f2h(acc[nc][mc][r]);
                    size_t idx = ((size_t)bh * NN + t) * HD + d0;
                    if (s == 0) *(us4*)(Q + idx) = h4;
                    else        *(us4*)(K + idx) = h4;
                } else {
#pragma unroll
                    for (int r = 0; r < 4; ++r) {
                        size_t idx = ((size_t)bh * HD + d0 + r) * NNP + t;
                        Vth[idx] = f2h(acc[nc][mc][r]);
                        if (t == NN - 1) {
#pragma unroll
                            for (int tt = 1; tt <= 7; ++tt) Vth[idx + tt] = 0;
                        }
                    }
                }
            }
        } else {
#pragma unroll
            for (int nc = 0; nc < 4; ++nc) {
                int n = n0 + wn * 64 + nc * 16 + ((lane >> 4) << 2);
                float4 o = {acc[nc][mc][0] + bias[n + 0], acc[nc][mc][1] + bias[n + 1],
                            acc[nc][mc][2] + bias[n + 2], acc[nc][mc][3] + bias[n + 3]};
                *(float4*)(fout + (size_t)m * CC + n) = o;
            }
        }
    }
}

// ---------------- norm_rope: single fp16 plane; fold 0.125*log2e into q ------------
__global__ __launch_bounds__(256) void norm_rope(us* __restrict__ Q, us* __restrict__ K,
                                                 const float* __restrict__ qw,
                                                 const float* __restrict__ kw) {
    const int lane = threadIdx.x & 63;
    const int widx = threadIdx.x >> 6;
    const int rid  = blockIdx.x * 4 + widx;
    const bool isq = (blockIdx.y == 0);
    us* Ph = (isq ? Q : K);
    const float* w = isq ? qw : kw;
    const int t = rid % NN;
    size_t base = (size_t)rid * HD + lane;

    float v = h2f(Ph[base]);
    float ss = v * v;
#pragma unroll
    for (int o = 32; o; o >>= 1) ss += __shfl_xor(ss, o);
    float r = 1.0f / sqrtf(ss * (1.0f / 64.0f) + 1e-6f);
    v = v * r * w[lane];

    float partner = __shfl_xor(v, 32);
    if (t > 0) {
        int p   = t - 1;
        int pos = (lane < 32) ? (p & 31) : (p >> 5);
        int j   = lane & 15;
        float invf = exp2f((float)j * (-13.287712379549449f / 16.0f));
        float ang  = (float)pos * invf;
        float c = cosf(ang), sn = sinf(ang);
        float rh = (lane < 32) ? -partner : partner;
        v = v * c + rh * sn;
    }
    if (isq) v *= 0.125f * 1.4426950408889634f;   // d^-0.5 and log2(e)
    Ph[base] = f2h(v);
}

// ---------------- attn: swapped-QK^T plain-fp16 MFMA flash attention ---------------
// LDS 24KB: K[0..8K) V[8K..16K) P per-wave [16K + wv*2K).
__global__ __launch_bounds__(256, 4) void attn_mfma(
    const us* __restrict__ Q, const us* __restrict__ K,
    const us* __restrict__ Vth, us* __restrict__ OC) {
    __shared__ __align__(16) char smem[24576];
    const int tid = threadIdx.x;
    const int lane = tid & 63, wv = tid >> 6;
    const int g = lane >> 4, qi = lane & 15;

    int lin = blockIdx.x;
    int xcd = lin & 7, loc = lin >> 3;
    int bh  = (loc / 17) * 8 + xcd;
    int qb  = loc - (loc / 17) * 17;
    const int q0 = qb * 64;

    const size_t kbase0 = (size_t)bh * NN * HD;
    const size_t vbase0 = (size_t)bh * HD * NNP;

    short8 qf[2];
    {
        int qr = imin(q0 + (wv << 4) + qi, NN - 1);
        const us* qp = Q + kbase0 + (size_t)qr * HD + (g << 3);
        qf[0] = *(const short8*)(qp);
        qf[1] = *(const short8*)(qp + 32);
    }

    f32x4 oa[4];
    const f32x4 fz = {0.f, 0.f, 0.f, 0.f};
#pragma unroll
    for (int db = 0; db < 4; ++db) oa[db] = fz;
    float m_r = -INFINITY;
    float l_r = 0.f;

    const int PB = 16384 + wv * 2048;

    short8 pkh[2], pvh[2];
    const int srow = (wv << 4) + (lane >> 3);
    const int sg   = lane & 7;
    auto issue_loads = [&](int j0) {
#pragma unroll
        for (int i = 0; i < 2; ++i) {
            int row = srow + (i << 3);
            int krow = imin(j0 + row, NN - 1);
            pkh[i] = *(const short8*)(K + kbase0 + (size_t)krow * HD + (sg << 3));
            int k0 = j0 + (sg << 3);
            if (k0 > 1024) k0 = 1024;
            pvh[i] = *(const short8*)(Vth + vbase0 + (size_t)row * NNP + k0);
        }
    };
    issue_loads(0);

    for (int t = 0; t < 17; ++t) {
        const int j0 = t * 64;
#pragma unroll
        for (int i = 0; i < 2; ++i) {
            int row = srow + (i << 3);
            int off = row * 128 + ((sg << 4) ^ ((row & 7) << 4));
            *(short8*)(smem + off)        = pkh[i];
            *(short8*)(smem + 8192 + off) = pvh[i];
        }
        __syncthreads();
        if (t < 16) issue_loads(j0 + 64);

        // S^T = K·Q (single fp16 product, swapped operands)
        f32x4 sc[4];
#pragma unroll
        for (int c = 0; c < 4; ++c) sc[c] = fz;
        __builtin_amdgcn_s_setprio(1);
#pragma unroll
        for (int ks = 0; ks < 2; ++ks) {
#pragma unroll
            for (int c = 0; c < 4; ++c) {
                int row  = (c << 4) + qi;
                int boff = row * 128 + (((ks << 6) + (g << 4)) ^ ((row & 7) << 4));
                short8 kfh = *(const short8*)(smem + boff);
                sc[c] = __builtin_amdgcn_mfma_f32_16x16x32_f16(kfh, qf[ks], sc[c], 0, 0, 0);
            }
        }
        __builtin_amdgcn_s_setprio(0);

        if (j0 + 64 > NN) {
#pragma unroll
            for (int c = 0; c < 4; ++c)
#pragma unroll
                for (int r = 0; r < 4; ++r)
                    if (j0 + (c << 4) + (g << 2) + r >= NN) sc[c][r] = -1e30f;
        }

        // per-lane row softmax (row q = lane&15, replicated over g)
        float rm = sc[0][0];
#pragma unroll
        for (int c = 0; c < 4; ++c)
#pragma unroll
            for (int r = 0; r < 4; ++r) rm = fmaxf(rm, sc[c][r]);
        rm = fmaxf(rm, __shfl_xor(rm, 16));
        rm = fmaxf(rm, __shfl_xor(rm, 32));
        float mnew = fmaxf(m_r, rm);
        float corr = exp2f(m_r - mnew);
        m_r = mnew;

        float p[4][4];
        float rs = 0.f;
#pragma unroll
        for (int c = 0; c < 4; ++c)
#pragma unroll
            for (int r = 0; r < 4; ++r) {
                p[c][r] = exp2f(sc[c][r] - mnew);
                rs += p[c][r];
            }
        rs += __shfl_xor(rs, 16);
        rs += __shfl_xor(rs, 32);
        l_r = l_r * corr + rs;

        // pack P (fp16 pairs) and write 4x b64 into swizzled [q][k] layout
#pragma unroll
        for (int c = 0; c < 4; ++c) {
            uint2 w;
            w.x = pkrtz(p[c][0], p[c][1]);
            w.y = pkrtz(p[c][2], p[c][3]);
            int off = PB + qi * 128 + ((((c << 1) + (g >> 1)) << 4) ^ ((qi & 7) << 4)) + ((g & 1) << 3);
            *(uint2*)(smem + off) = w;
        }

        // rescale O accumulator
#pragma unroll
        for (int r = 0; r < 4; ++r) {
            float cr = __shfl(corr, (g << 2) + r);
#pragma unroll
            for (int db = 0; db < 4; ++db) oa[db][r] *= cr;
        }

        // O += P·V (single fp16 product)
        __builtin_amdgcn_s_setprio(1);
#pragma unroll
        for (int ks = 0; ks < 2; ++ks) {
            int poff = PB + qi * 128 + (((ks << 6) + (g << 4)) ^ ((qi & 7) << 4));
            short8 pah = *(const short8*)(smem + poff);
#pragma unroll
            for (int db = 0; db < 4; ++db) {
                int vrow = (db << 4) + qi;
                int voff = 8192 + vrow * 128 + (((ks << 6) + (g << 4)) ^ ((vrow & 7) << 4));
                short8 vfh = *(const short8*)(smem + voff);
                oa[db] = __builtin_amdgcn_mfma_f32_16x16x32_f16(pah, vfh, oa[db], 0, 0, 0);
            }
        }
        __builtin_amdgcn_s_setprio(0);
        __syncthreads();
    }

    const int b = bh / NHEADS, h = bh - b * NHEADS;
#pragma unroll
    for (int r = 0; r < 4; ++r) {
        int q = q0 + (wv << 4) + (g << 2) + r;
        float linv = 1.0f / __shfl(l_r, (g << 2) + r);
        if (q < NN) {
#pragma unroll
            for (int db = 0; db < 4; ++db) {
                int d = (db << 4) + qi;
                int dg = h * HD + d;
                OC[(size_t)(b * NN + q) * CC + dg] = f2h(oa[db][r] * linv);
            }
        }
    }
}

extern "C" void kernel_launch(void* const* d_in, const int* in_sizes, int n_in,
                              void* d_out, int out_size, void* d_ws, size_t ws_size,
                              hipStream_t stream) {
    const float* x      = (const float*)d_in[0];
    const float* qkv_w  = (const float*)d_in[1];
    const float* proj_w = (const float*)d_in[2];
    const float* proj_b = (const float*)d_in[3];
    const float* qnw    = (const float*)d_in[4];
    const float* knw    = (const float*)d_in[5];

    us* p = (us*)d_ws;
    us* Q   = p;                 p += QSZ;
    us* K   = p;                 p += QSZ;
    us* Vth = p;                 p += VTSZ;
    us* XC  = p;                 p += (size_t)MM * CC;     // plain fp16 X; reused as O
    us* WC  = p;                 p += (size_t)3 * CC * CC; // qkv W^T plain fp16
    us* PC  = p;                 p += (size_t)CC * CC;     // proj W^T plain fp16

    split_x<<<dim3((int)(((size_t)MM * CC) / 8 / 256)), 256, 0, stream>>>(x, XC);
    tsplit<<<dim3(3 * CC / 64, CC / 64), 256, 0, stream>>>(qkv_w, WC, 3 * CC);
    tsplit<<<dim3(CC / 64, CC / 64), 256, 0, stream>>>(proj_w, PC, CC);

    gemm_mfma<0><<<dim3(3 * CC / 128, (MM + 127) / 128), 256, 0, stream>>>(
        WC, XC, Q, K, Vth, nullptr, nullptr);
    norm_rope<<<dim3(BB * NHEADS * NN / 4, 2), 256, 0, stream>>>(Q, K, qnw, knw);
    attn_mfma<<<dim3(8 * 408), 256, 0, stream>>>(Q, K, Vth, XC);
    gemm_mfma<1><<<dim3(CC / 128, (MM + 127) / 128), 256, 0, stream>>>(
        PC, XC, nullptr, nullptr, nullptr,
        (float*)d_out, proj_b);
}

// Round 14
// 313.796 us; speedup vs baseline: 2.5376x; 1.0588x over previous
//
#include <hip/hip_runtime.h>
#include <math.h>

#define NHEADS 12
#define HD 64
#define BB 16
#define NN 1025
#define CC 768
#define MM (BB * NN)                       // 16400
#define QSZ ((size_t)BB * NHEADS * NN * HD)   // 12,595,200
#define NNP 1032                           // padded t-stride for V^T
#define VTSZ ((size_t)BB * NHEADS * HD * NNP)

typedef __attribute__((ext_vector_type(8))) short short8;
typedef __attribute__((ext_vector_type(4))) float f32x4;
typedef __attribute__((ext_vector_type(4))) unsigned short us4;
typedef unsigned short us;

typedef __attribute__((address_space(3))) unsigned int lds_u32;
typedef const __attribute__((address_space(1))) unsigned int g_u32;

__device__ __forceinline__ void gload16(const void* g, void* l) {
    __builtin_amdgcn_global_load_lds((g_u32*)g, (lds_u32*)l, 16, 0, 0);
}

__device__ __forceinline__ int imin(int a, int b) { return a < b ? a : b; }

__device__ __forceinline__ us f2h(float f) {          // fp32 -> fp16 bits (RTE)
    _Float16 h = (_Float16)f;
    return __builtin_bit_cast(unsigned short, h);
}
__device__ __forceinline__ float h2f(us b) {
    return (float)__builtin_bit_cast(_Float16, b);
}
__device__ __forceinline__ unsigned pkrtz(float a, float b) {  // 2xfp16 packed
    return __builtin_bit_cast(unsigned, __builtin_amdgcn_cvt_pkrtz(a, b));
}

// ---------------- split_x: fp32 -> plain fp16 [M][768] -----------------------------
__global__ __launch_bounds__(256) void split_x(const float* __restrict__ src,
                                               us* __restrict__ xc) {
    size_t e = ((size_t)blockIdx.x * 256 + threadIdx.x) * 8;
    float4 a = *(const float4*)(src + e);
    float4 b = *(const float4*)(src + e + 4);
    float v[8] = {a.x, a.y, a.z, a.w, b.x, b.y, b.z, b.w};
    short8 h;
#pragma unroll
    for (int j = 0; j < 8; ++j) h[j] = (short)f2h(v[j]);
    *(short8*)(xc + e) = h;
}

// ---------------- tsplit: W [K][N] fp32 -> W^T plain fp16 [N][K] -------------------
__global__ __launch_bounds__(256) void tsplit(const float* __restrict__ w,
                                              us* __restrict__ wc, int N) {
    __shared__ float tile[64][65];
    const int t = threadIdx.x;
    const int n0 = blockIdx.x * 64, k0 = blockIdx.y * 64;
    {
        int kr = t & 63, so = t >> 6;
#pragma unroll
        for (int g = 0; g < 4; ++g) {
            int c = (so * 4 + g) * 4;
            float4 v = *(const float4*)(w + (size_t)(k0 + kr) * N + n0 + c);
            tile[kr][c + 0] = v.x; tile[kr][c + 1] = v.y;
            tile[kr][c + 2] = v.z; tile[kr][c + 3] = v.w;
        }
    }
    __syncthreads();
    int nr = t & 63, half = t >> 6;     // 16 consecutive k per thread
    short8 h0, h1;
#pragma unroll
    for (int j = 0; j < 8; ++j) h0[j] = (short)f2h(tile[half * 16 + j][nr]);
#pragma unroll
    for (int j = 0; j < 8; ++j) h1[j] = (short)f2h(tile[half * 16 + 8 + j][nr]);
    size_t o = (size_t)(n0 + nr) * CC + k0 + half * 16;
    *(short8*)(wc + o)     = h0;
    *(short8*)(wc + o + 8) = h1;
}

// ---------------- gemm_mfma: plain fp16 single-product, BK=64, gload_lds -----------
// A/B LDS: 128 rows x 128B (8 slots of 16B, slot s holds chunk s^(row&7)).
template<int MODE>
__global__ __launch_bounds__(256) void gemm_mfma(
    const us* __restrict__ A,      // W^T plain fp16 [N][768]
    const us* __restrict__ B,      // X/O plain fp16 [M][768]
    us* __restrict__ Q, us* __restrict__ K, us* __restrict__ Vth,
    float* __restrict__ fout, const float* __restrict__ bias) {
    __shared__ __align__(16) char lds[32768];
    char* ldsA = lds;              // 16 KB
    char* ldsB = lds + 16384;      // 16 KB
    const int tid = threadIdx.x;
    const int lane = tid & 63, wv = tid >> 6;
    const int wn = wv >> 1, wm = wv & 1;
    const int n0 = blockIdx.x * 128, m0 = blockIdx.y * 128;

    f32x4 acc[4][4];
    const f32x4 fz = {0.f, 0.f, 0.f, 0.f};
#pragma unroll
    for (int a = 0; a < 4; ++a)
#pragma unroll
        for (int b = 0; b < 4; ++b) acc[a][b] = fz;

    // staging: iter i -> row = i*32 + wv*8 + (lane>>3), slot = lane&7,
    // source chunk = slot ^ ((lane>>3)&7)   (i-invariant: i*32, wv*8 ≡ 0 mod 8)
    const int srow = (wv << 3) + (lane >> 3);
    const int cb   = (lane & 7) ^ ((lane >> 3) & 7);
    size_t aoff[4], boff[4];
#pragma unroll
    for (int i = 0; i < 4; ++i) {
        aoff[i] = (size_t)(n0 + srow + i * 32) * CC + cb * 8;
        boff[i] = (size_t)imin(m0 + srow + i * 32, MM - 1) * CC + cb * 8;
    }
    const int wdst = wv * 1024;

    for (int t = 0; t < CC / 64; ++t) {
#pragma unroll
        for (int i = 0; i < 4; ++i) {
            gload16(A + aoff[i] + t * 64, ldsA + i * 4096 + wdst);
            gload16(B + boff[i] + t * 64, ldsB + i * 4096 + wdst);
        }
        __syncthreads();   // drains vmcnt -> tile valid

        const int j  = lane >> 4;
        const int rl = lane & 15;
#pragma unroll
        for (int kh = 0; kh < 2; ++kh) {
            short8 af[4];
#pragma unroll
            for (int nc = 0; nc < 4; ++nc) {
                int ra = wn * 64 + nc * 16 + rl;
                af[nc] = *(const short8*)(ldsA + ra * 128 + ((((kh << 2) + j) ^ (ra & 7)) << 4));
            }
            __builtin_amdgcn_s_setprio(1);
#pragma unroll
            for (int mc = 0; mc < 4; ++mc) {
                int rb = wm * 64 + mc * 16 + rl;
                short8 bf = *(const short8*)(ldsB + rb * 128 + ((((kh << 2) + j) ^ (rb & 7)) << 4));
#pragma unroll
                for (int nc = 0; nc < 4; ++nc)
                    acc[nc][mc] = __builtin_amdgcn_mfma_f32_16x16x32_f16(af[nc], bf, acc[nc][mc], 0, 0, 0);
            }
            __builtin_amdgcn_s_setprio(0);
        }
        __syncthreads();
    }

#pragma unroll
    for (int mc = 0; mc < 4; ++mc) {
        int m = m0 + wm * 64 + mc * 16 + (lane & 15);
        if (m >= MM) continue;
        if (MODE == 0) {
            int b = m / NN, t = m - b * NN;
#pragma unroll
            for (int nc = 0; nc < 4; ++nc) {
                int n = n0 + wn * 64 + nc * 16 + ((lane >> 4) << 2);
                int s = n0 / CC;
                int nin = n - s * CC;
                int head = nin >> 6, d0 = nin & 63;
                int bh = b * NHEADS + head;
                if (s < 2) {
                    us4 h4;
#pragma unroll
                    for (int r = 0; r < 4; ++r) h4[r] = f2h(acc[nc][mc][r]);
                    size_t idx = ((size_t)bh * NN + t) * HD + d0;
                    if (s == 0) *(us4*)(Q + idx) = h4;
                    else        *(us4*)(K + idx) = h4;
                } else {
#pragma unroll
                    for (int r = 0; r < 4; ++r) {
                        size_t idx = ((size_t)bh * HD + d0 + r) * NNP + t;
                        Vth[idx] = f2h(acc[nc][mc][r]);
                        if (t == NN - 1) {
#pragma unroll
                            for (int tt = 1; tt <= 7; ++tt) Vth[idx + tt] = 0;
                        }
                    }
                }
            }
        } else {
#pragma unroll
            for (int nc = 0; nc < 4; ++nc) {
                int n = n0 + wn * 64 + nc * 16 + ((lane >> 4) << 2);
                float4 o = {acc[nc][mc][0] + bias[n + 0], acc[nc][mc][1] + bias[n + 1],
                            acc[nc][mc][2] + bias[n + 2], acc[nc][mc][3] + bias[n + 3]};
                *(float4*)(fout + (size_t)m * CC + n) = o;
            }
        }
    }
}

// ---------------- norm_rope: single fp16 plane; fold 0.125*log2e into q ------------
__global__ __launch_bounds__(256) void norm_rope(us* __restrict__ Q, us* __restrict__ K,
                                                 const float* __restrict__ qw,
                                                 const float* __restrict__ kw) {
    const int lane = threadIdx.x & 63;
    const int widx = threadIdx.x >> 6;
    const int rid  = blockIdx.x * 4 + widx;
    const bool isq = (blockIdx.y == 0);
    us* Ph = (isq ? Q : K);
    const float* w = isq ? qw : kw;
    const int t = rid % NN;
    size_t base = (size_t)rid * HD + lane;

    float v = h2f(Ph[base]);
    float ss = v * v;
#pragma unroll
    for (int o = 32; o; o >>= 1) ss += __shfl_xor(ss, o);
    float r = 1.0f / sqrtf(ss * (1.0f / 64.0f) + 1e-6f);
    v = v * r * w[lane];

    float partner = __shfl_xor(v, 32);
    if (t > 0) {
        int p   = t - 1;
        int pos = (lane < 32) ? (p & 31) : (p >> 5);
        int j   = lane & 15;
        float invf = exp2f((float)j * (-13.287712379549449f / 16.0f));
        float ang  = (float)pos * invf;
        float c = cosf(ang), sn = sinf(ang);
        float rh = (lane < 32) ? -partner : partner;
        v = v * c + rh * sn;
    }
    if (isq) v *= 0.125f * 1.4426950408889634f;   // d^-0.5 and log2(e)
    Ph[base] = f2h(v);
}

// ---------------- attn: swapped-QK^T, boundless softmax (|s|<=11.56 provable) ------
// p = exp2(s) directly: p in [2^-11.6, 2^11.6] — fp16-normal, no overflow.
// No max tracking, no O rescale; l reduced across g-groups once at the end.
__global__ __launch_bounds__(256, 4) void attn_mfma(
    const us* __restrict__ Q, const us* __restrict__ K,
    const us* __restrict__ Vth, us* __restrict__ OC) {
    __shared__ __align__(16) char smem[24576];
    const int tid = threadIdx.x;
    const int lane = tid & 63, wv = tid >> 6;
    const int g = lane >> 4, qi = lane & 15;

    int lin = blockIdx.x;
    int xcd = lin & 7, loc = lin >> 3;
    int bh  = (loc / 17) * 8 + xcd;
    int qb  = loc - (loc / 17) * 17;
    const int q0 = qb * 64;

    const size_t kbase0 = (size_t)bh * NN * HD;
    const size_t vbase0 = (size_t)bh * HD * NNP;

    short8 qf[2];
    {
        int qr = imin(q0 + (wv << 4) + qi, NN - 1);
        const us* qp = Q + kbase0 + (size_t)qr * HD + (g << 3);
        qf[0] = *(const short8*)(qp);
        qf[1] = *(const short8*)(qp + 32);
    }

    f32x4 oa[4];
    const f32x4 fz = {0.f, 0.f, 0.f, 0.f};
#pragma unroll
    for (int db = 0; db < 4; ++db) oa[db] = fz;
    float l_r = 0.f;          // per-lane partial of row qi's denominator

    const int PB = 16384 + wv * 2048;

    short8 pkh[2], pvh[2];
    const int srow = (wv << 4) + (lane >> 3);
    const int sg   = lane & 7;
    auto issue_loads = [&](int j0) {
#pragma unroll
        for (int i = 0; i < 2; ++i) {
            int row = srow + (i << 3);
            int krow = imin(j0 + row, NN - 1);
            pkh[i] = *(const short8*)(K + kbase0 + (size_t)krow * HD + (sg << 3));
            int k0 = j0 + (sg << 3);
            if (k0 > 1024) k0 = 1024;
            pvh[i] = *(const short8*)(Vth + vbase0 + (size_t)row * NNP + k0);
        }
    };
    issue_loads(0);

    for (int t = 0; t < 17; ++t) {
        const int j0 = t * 64;
#pragma unroll
        for (int i = 0; i < 2; ++i) {
            int row = srow + (i << 3);
            int off = row * 128 + ((sg << 4) ^ ((row & 7) << 4));
            *(short8*)(smem + off)        = pkh[i];
            *(short8*)(smem + 8192 + off) = pvh[i];
        }
        __syncthreads();
        if (t < 16) issue_loads(j0 + 64);

        // S^T = K·Q (single fp16 product, swapped operands)
        f32x4 sc[4];
#pragma unroll
        for (int c = 0; c < 4; ++c) sc[c] = fz;
        __builtin_amdgcn_s_setprio(1);
#pragma unroll
        for (int ks = 0; ks < 2; ++ks) {
#pragma unroll
            for (int c = 0; c < 4; ++c) {
                int row  = (c << 4) + qi;
                int boff = row * 128 + (((ks << 6) + (g << 4)) ^ ((row & 7) << 4));
                short8 kfh = *(const short8*)(smem + boff);
                sc[c] = __builtin_amdgcn_mfma_f32_16x16x32_f16(kfh, qf[ks], sc[c], 0, 0, 0);
            }
        }
        __builtin_amdgcn_s_setprio(0);

        if (j0 + 64 > NN) {
#pragma unroll
            for (int c = 0; c < 4; ++c)
#pragma unroll
                for (int r = 0; r < 4; ++r)
                    if (j0 + (c << 4) + (g << 2) + r >= NN) sc[c][r] = -1e30f;
        }

        // boundless softmax: p = exp2(s); accumulate per-lane partial denom
        float p[4][4];
#pragma unroll
        for (int c = 0; c < 4; ++c)
#pragma unroll
            for (int r = 0; r < 4; ++r) {
                p[c][r] = exp2f(sc[c][r]);
                l_r += p[c][r];
            }

        // pack P (fp16 pairs) and write 4x b64 into swizzled [q][k] layout
#pragma unroll
        for (int c = 0; c < 4; ++c) {
            uint2 w;
            w.x = pkrtz(p[c][0], p[c][1]);
            w.y = pkrtz(p[c][2], p[c][3]);
            int off = PB + qi * 128 + ((((c << 1) + (g >> 1)) << 4) ^ ((qi & 7) << 4)) + ((g & 1) << 3);
            *(uint2*)(smem + off) = w;
        }

        // O += P·V (single fp16 product; no rescale needed)
        __builtin_amdgcn_s_setprio(1);
#pragma unroll
        for (int ks = 0; ks < 2; ++ks) {
            int poff = PB + qi * 128 + (((ks << 6) + (g << 4)) ^ ((qi & 7) << 4));
            short8 pah = *(const short8*)(smem + poff);
#pragma unroll
            for (int db = 0; db < 4; ++db) {
                int vrow = (db << 4) + qi;
                int voff = 8192 + vrow * 128 + (((ks << 6) + (g << 4)) ^ ((vrow & 7) << 4));
                short8 vfh = *(const short8*)(smem + voff);
                oa[db] = __builtin_amdgcn_mfma_f32_16x16x32_f16(pah, vfh, oa[db], 0, 0, 0);
            }
        }
        __builtin_amdgcn_s_setprio(0);
        __syncthreads();
    }

    // g-group reduction of the denominator (once)
    l_r += __shfl_xor(l_r, 16);
    l_r += __shfl_xor(l_r, 32);

    const int b = bh / NHEADS, h = bh - b * NHEADS;
#pragma unroll
    for (int r = 0; r < 4; ++r) {
        int q = q0 + (wv << 4) + (g << 2) + r;
        float linv = 1.0f / __shfl(l_r, (g << 2) + r);
        if (q < NN) {
#pragma unroll
            for (int db = 0; db < 4; ++db) {
                int d = (db << 4) + qi;
                int dg = h * HD + d;
                OC[(size_t)(b * NN + q) * CC + dg] = f2h(oa[db][r] * linv);
            }
        }
    }
}

extern "C" void kernel_launch(void* const* d_in, const int* in_sizes, int n_in,
                              void* d_out, int out_size, void* d_ws, size_t ws_size,
                              hipStream_t stream) {
    const float* x      = (const float*)d_in[0];
    const float* qkv_w  = (const float*)d_in[1];
    const float* proj_w = (const float*)d_in[2];
    const float* proj_b = (const float*)d_in[3];
    const float* qnw    = (const float*)d_in[4];
    const float* knw    = (const float*)d_in[5];

    us* p = (us*)d_ws;
    us* Q   = p;                 p += QSZ;
    us* K   = p;                 p += QSZ;
    us* Vth = p;                 p += VTSZ;
    us* XC  = p;                 p += (size_t)MM * CC;     // plain fp16 X; reused as O
    us* WC  = p;                 p += (size_t)3 * CC * CC; // qkv W^T plain fp16
    us* PC  = p;                 p += (size_t)CC * CC;     // proj W^T plain fp16

    split_x<<<dim3((int)(((size_t)MM * CC) / 8 / 256)), 256, 0, stream>>>(x, XC);
    tsplit<<<dim3(3 * CC / 64, CC / 64), 256, 0, stream>>>(qkv_w, WC, 3 * CC);
    tsplit<<<dim3(CC / 64, CC / 64), 256, 0, stream>>>(proj_w, PC, CC);

    gemm_mfma<0><<<dim3(3 * CC / 128, (MM + 127) / 128), 256, 0, stream>>>(
        WC, XC, Q, K, Vth, nullptr, nullptr);
    norm_rope<<<dim3(BB * NHEADS * NN / 4, 2), 256, 0, stream>>>(Q, K, qnw, knw);
    attn_mfma<<<dim3(8 * 408), 256, 0, stream>>>(Q, K, Vth, XC);
    gemm_mfma<1><<<dim3(CC / 128, (MM + 127) / 128), 256, 0, stream>>>(
        PC, XC, nullptr, nullptr, nullptr,
        (float*)d_out, proj_b);
}